// Round 13
// baseline (1115.593 us; speedup 1.0000x reference)
//
#include <hip/hip_runtime.h>
#include <hip/hip_bf16.h>

#define NP     100000   // n_paths
#define PLEN   5        // path length
#define NLINKS 10000    // n_links
#define DIM    32       // state dim
#define TITERS 8        // message passing iterations
#define E_TOT  (NP * PLEN)

using bf16x8 = __attribute__((ext_vector_type(8))) short;
using f32x4  = __attribute__((ext_vector_type(4))) float;
union FragCast { uint4 u; bf16x8 v; };

// ---------- helpers ----------
__device__ __forceinline__ float fast_sigmoid(float v) {
    return 1.0f / (1.0f + __expf(-v));
}
__device__ __forceinline__ float fast_tanh(float v) {
    float e = __expf(-2.0f * fabsf(v));
    float t = (1.0f - e) / (1.0f + e);
    return v >= 0.0f ? t : -t;
}
__device__ __forceinline__ float seluf(float v) {
    const float sc = 1.0507009873554805f;
    const float al = 1.6732632423543772f;
    return v > 0.0f ? sc * v : sc * al * (__expf(v) - 1.0f);
}
__device__ __forceinline__ unsigned short f2bf(float f) {
    union { float f; unsigned u; } c; c.f = f;
    unsigned u = c.u;
    return (unsigned short)((u + 0x7fffu + ((u >> 16) & 1u)) >> 16);
}
__device__ __forceinline__ float bf2f(unsigned short b) {
    union { unsigned u; float f; } c; c.u = ((unsigned)b) << 16;
    return c.f;
}
__device__ __forceinline__ void split_bf16(const float (&v)[8], bf16x8& hi, bf16x8& lo) {
    unsigned uh[4], ul[4];
    #pragma unroll
    for (int i = 0; i < 4; ++i) {
        unsigned short h0 = f2bf(v[2*i]),   h1 = f2bf(v[2*i+1]);
        float r0 = v[2*i] - bf2f(h0),       r1 = v[2*i+1] - bf2f(h1);
        unsigned short l0 = f2bf(r0),       l1 = f2bf(r1);
        uh[i] = (unsigned)h0 | ((unsigned)h1 << 16);
        ul[i] = (unsigned)l0 | ((unsigned)l1 << 16);
    }
    FragCast ch, cl;
    ch.u.x = uh[0]; ch.u.y = uh[1]; ch.u.z = uh[2]; ch.u.w = uh[3];
    cl.u.x = ul[0]; cl.u.y = ul[1]; cl.u.z = ul[2]; cl.u.w = ul[3];
    hi = ch.v; lo = cl.v;
}

// ---------- init (also writes hi/lo split of initial link_state) ----------
__global__ __launch_bounds__(256) void init_kernel(
    const float* __restrict__ cap, const float* __restrict__ pol, const float* __restrict__ wts,
    const float* __restrict__ bw,  const float* __restrict__ tos,
    const float* __restrict__ pk,  const float* __restrict__ avg,
    float* __restrict__ link_state, float* __restrict__ path_state,
    unsigned short* __restrict__ ls_hi, unsigned short* __restrict__ ls_lo)
{
    int i = blockIdx.x * 256 + threadIdx.x;
    if (i < NLINKS) {
        float row[DIM];
        #pragma unroll
        for (int c = 0; c < DIM; ++c) row[c] = 0.0f;
        row[0] = cap[i]; row[1] = pol[i]; row[2] = wts[i];
        float4* o = (float4*)(link_state + (size_t)i * DIM);
        #pragma unroll
        for (int c = 0; c < 8; ++c) {
            float4 v = { row[4*c], row[4*c+1], row[4*c+2], row[4*c+3] };
            o[c] = v;
        }
        unsigned ush[16], usl[16];
        #pragma unroll
        for (int c = 0; c < 16; ++c) {
            unsigned short h0 = f2bf(row[2*c]), h1 = f2bf(row[2*c+1]);
            unsigned short l0 = f2bf(row[2*c] - bf2f(h0));
            unsigned short l1 = f2bf(row[2*c+1] - bf2f(h1));
            ush[c] = (unsigned)h0 | ((unsigned)h1 << 16);
            usl[c] = (unsigned)l0 | ((unsigned)l1 << 16);
        }
        uint4* oh = (uint4*)(ls_hi + (size_t)i * DIM);
        uint4* ol = (uint4*)(ls_lo + (size_t)i * DIM);
        #pragma unroll
        for (int q = 0; q < 4; ++q) {
            uint4 vh = { ush[4*q], ush[4*q+1], ush[4*q+2], ush[4*q+3] };
            uint4 vl = { usl[4*q], usl[4*q+1], usl[4*q+2], usl[4*q+3] };
            oh[q] = vh; ol[q] = vl;
        }
    }
    if (i < NP) {
        float row[DIM];
        #pragma unroll
        for (int c = 0; c < DIM; ++c) row[c] = 0.0f;
        row[0] = bw[i]; row[1] = tos[i]; row[2] = pk[i]; row[3] = avg[i];
        float4* o = (float4*)(path_state + (size_t)i * DIM);
        #pragma unroll
        for (int c = 0; c < 8; ++c) {
            float4 v = { row[4*c], row[4*c+1], row[4*c+2], row[4*c+3] };
            o[c] = v;
        }
    }
}

// ---------- CSR build ----------
__global__ __launch_bounds__(256) void csr_count(const int* __restrict__ links,
                                                 int* __restrict__ cnt)
{
    int e = blockIdx.x * 256 + threadIdx.x;
    if (e < E_TOT) atomicAdd(&cnt[links[e]], 1);
}

__global__ __launch_bounds__(256) void csr_scan(const int* __restrict__ cnt,
                                                int* __restrict__ row_start,
                                                int* __restrict__ cursor)
{
    __shared__ int s[256];
    int t = threadIdx.x;
    int carry = 0;
    for (int base = 0; base < NLINKS; base += 256) {
        int i = base + t;
        int v = (i < NLINKS) ? cnt[i] : 0;
        s[t] = v;
        __syncthreads();
        for (int off = 1; off < 256; off <<= 1) {
            int tv = (t >= off) ? s[t - off] : 0;
            __syncthreads();
            s[t] += tv;
            __syncthreads();
        }
        int excl = s[t] - v;
        if (i < NLINKS) { row_start[i] = carry + excl; cursor[i] = carry + excl; }
        int tot = s[255];
        __syncthreads();
        carry += tot;
    }
    if (t == 0) row_start[NLINKS] = carry;
}

__global__ __launch_bounds__(256) void csr_scatter(const int* __restrict__ links,
                                                   int* __restrict__ cursor,
                                                   int* __restrict__ slot)
{
    int e = blockIdx.x * 256 + threadIdx.x;
    if (e < E_TOT) slot[e] = atomicAdd(&cursor[links[e]], 1);
}

// ---------- once per launch: GRU weights -> MFMA B-frags (hi/lo) ----------
// generic: used for (Wp,Up)->wfr and (Wl,Ul)->lfr
__global__ __launch_bounds__(256) void wprep_kernel(const float* __restrict__ W,
                                                    const float* __restrict__ U,
                                                    unsigned short* __restrict__ ofr)
{
    int idx = blockIdx.x * 256 + threadIdx.x;
    if (idx >= 6 * 64 * 8) return;
    int j = idx & 7, lane = (idx >> 3) & 63, g = idx >> 9;
    int k = (lane >> 4) * 8 + j;
    int n = g * 16 + (lane & 15);
    float w = W[k * 96 + n];
    float u = U[k * 96 + n];
    unsigned short whi = f2bf(w); unsigned short wlo = f2bf(w - bf2f(whi));
    unsigned short uhi = f2bf(u); unsigned short ulo = f2bf(u - bf2f(uhi));
    ofr[0 * 3072 + idx] = whi;
    ofr[1 * 3072 + idx] = wlo;
    ofr[2 * 3072 + idx] = uhi;
    ofr[3 * 3072 + idx] = ulo;
}

// ---------- once per launch: readout R1/R2 -> MFMA B-frags (hi/lo) ----------
__global__ __launch_bounds__(256) void rprep_kernel(const float* __restrict__ R1,
                                                    const float* __restrict__ R2,
                                                    unsigned short* __restrict__ rfr)
{
    int idx = blockIdx.x * 256 + threadIdx.x;
    if (idx >= 8192 + 65536) return;
    if (idx < 8192) {
        int j = idx & 7, lane = (idx >> 3) & 63, g = idx >> 9;
        int k = (lane >> 4) * 8 + j;
        int n = g * 16 + (lane & 15);
        float v = R1[k * 256 + n];
        unsigned short hi = f2bf(v);
        rfr[idx] = hi;
        rfr[8192 + idx] = f2bf(v - bf2f(hi));
    } else {
        int idx2 = idx - 8192;
        int j = idx2 & 7, lane = (idx2 >> 3) & 63, tile = idx2 >> 9;
        int c = tile >> 4, g = tile & 15;
        int k = c * 32 + (lane >> 4) * 8 + j;
        int n = g * 16 + (lane & 15);
        float v = R2[k * 256 + n];
        unsigned short hi = f2bf(v);
        rfr[16384 + idx2] = hi;
        rfr[16384 + 65536 + idx2] = f2bf(v - bf2f(hi));
    }
}

// ---------- MFMA path GRU (R11/R12-proven, unchanged) ----------
template <bool STORE_M>
__global__ __launch_bounds__(256) void path_kernel(
    const int*   __restrict__ links,
    const unsigned short* __restrict__ wfr,
    const float* __restrict__ bp,
    const unsigned short* __restrict__ ls_hi,
    const unsigned short* __restrict__ ls_lo,
    const int*   __restrict__ slot,
    float* __restrict__ path_state,
    float* __restrict__ m)
{
    __shared__ __align__(16) float T4[4][16 * 36];
    int t = threadIdx.x;
    int wave = t >> 6, lane = t & 63;
    int l15 = lane & 15, quad = lane >> 4;
    int p0 = (blockIdx.x * 4 + wave) * 16;
    if (p0 >= NP) return;
    float* T = T4[wave];
    int p = p0 + l15;

    int lk[PLEN];
    #pragma unroll
    for (int l = 0; l < PLEN; ++l) lk[l] = links[p * PLEN + l];
    bf16x8 pxh[PLEN], pxl[PLEN];
    #pragma unroll
    for (int l = 0; l < PLEN; ++l) {
        FragCast ch, cl;
        ch.u = *(const uint4*)(ls_hi + (size_t)lk[l] * DIM + quad * 8);
        cl.u = *(const uint4*)(ls_lo + (size_t)lk[l] * DIM + quad * 8);
        pxh[l] = ch.v; pxl[l] = cl.v;
    }
    int sl[PLEN];
    if (STORE_M) {
        #pragma unroll
        for (int l = 0; l < PLEN; ++l) sl[l] = slot[p * PLEN + l];
    }

    bf16x8 Wh[6], Wl[6], Uh[6], Ul[6];
    {
        const uint4* base = (const uint4*)wfr;
        #pragma unroll
        for (int g = 0; g < 6; ++g) {
            FragCast a;
            a.u = base[0 * 384 + g * 64 + lane]; Wh[g] = a.v;
            a.u = base[1 * 384 + g * 64 + lane]; Wl[g] = a.v;
            a.u = base[2 * 384 + g * 64 + lane]; Uh[g] = a.v;
            a.u = base[3 * 384 + g * 64 + lane]; Ul[g] = a.v;
        }
    }
    float bz[2], br[2], bnx[2], bnh[2];
    #pragma unroll
    for (int hf = 0; hf < 2; ++hf) {
        int c = hf * 16 + l15;
        bz[hf]  = bp[c]      + bp[96 + c];
        br[hf]  = bp[32 + c] + bp[96 + 32 + c];
        bnx[hf] = bp[64 + c];
        bnh[hf] = bp[96 + 64 + c];
    }

    float hA[8];
    {
        const float4* src = (const float4*)(path_state + (size_t)p * DIM + quad * 8);
        float4 v0 = src[0], v1 = src[1];
        hA[0]=v0.x; hA[1]=v0.y; hA[2]=v0.z; hA[3]=v0.w;
        hA[4]=v1.x; hA[5]=v1.y; hA[6]=v1.z; hA[7]=v1.w;
    }
    #pragma unroll
    for (int j = 0; j < 8; ++j) T[l15 * 36 + quad * 8 + j] = hA[j];
    __asm__ volatile("s_waitcnt lgkmcnt(0)" ::: "memory");
    float hC[2][4];
    #pragma unroll
    for (int hf = 0; hf < 2; ++hf)
        #pragma unroll
        for (int rg = 0; rg < 4; ++rg)
            hC[hf][rg] = T[(quad * 4 + rg) * 36 + hf * 16 + l15];

    bf16x8 ah, al;
    split_bf16(hA, ah, al);

    #pragma unroll
    for (int l = 0; l < PLEN; ++l) {
        bf16x8 xh = pxh[l], xl = pxl[l];
        #pragma unroll
        for (int hf = 0; hf < 2; ++hf) {
            f32x4 az = {0.f,0.f,0.f,0.f}, ar = {0.f,0.f,0.f,0.f};
            f32x4 axn = {0.f,0.f,0.f,0.f}, ahg = {0.f,0.f,0.f,0.f};
            int gz = hf, gr = 2 + hf, gn = 4 + hf;
            az = __builtin_amdgcn_mfma_f32_16x16x32_bf16(xh, Wh[gz], az, 0, 0, 0);
            az = __builtin_amdgcn_mfma_f32_16x16x32_bf16(xh, Wl[gz], az, 0, 0, 0);
            az = __builtin_amdgcn_mfma_f32_16x16x32_bf16(xl, Wh[gz], az, 0, 0, 0);
            az = __builtin_amdgcn_mfma_f32_16x16x32_bf16(ah, Uh[gz], az, 0, 0, 0);
            az = __builtin_amdgcn_mfma_f32_16x16x32_bf16(ah, Ul[gz], az, 0, 0, 0);
            az = __builtin_amdgcn_mfma_f32_16x16x32_bf16(al, Uh[gz], az, 0, 0, 0);
            ar = __builtin_amdgcn_mfma_f32_16x16x32_bf16(xh, Wh[gr], ar, 0, 0, 0);
            ar = __builtin_amdgcn_mfma_f32_16x16x32_bf16(xh, Wl[gr], ar, 0, 0, 0);
            ar = __builtin_amdgcn_mfma_f32_16x16x32_bf16(xl, Wh[gr], ar, 0, 0, 0);
            ar = __builtin_amdgcn_mfma_f32_16x16x32_bf16(ah, Uh[gr], ar, 0, 0, 0);
            ar = __builtin_amdgcn_mfma_f32_16x16x32_bf16(ah, Ul[gr], ar, 0, 0, 0);
            ar = __builtin_amdgcn_mfma_f32_16x16x32_bf16(al, Uh[gr], ar, 0, 0, 0);
            axn = __builtin_amdgcn_mfma_f32_16x16x32_bf16(xh, Wh[gn], axn, 0, 0, 0);
            axn = __builtin_amdgcn_mfma_f32_16x16x32_bf16(xh, Wl[gn], axn, 0, 0, 0);
            axn = __builtin_amdgcn_mfma_f32_16x16x32_bf16(xl, Wh[gn], axn, 0, 0, 0);
            ahg = __builtin_amdgcn_mfma_f32_16x16x32_bf16(ah, Uh[gn], ahg, 0, 0, 0);
            ahg = __builtin_amdgcn_mfma_f32_16x16x32_bf16(ah, Ul[gn], ahg, 0, 0, 0);
            ahg = __builtin_amdgcn_mfma_f32_16x16x32_bf16(al, Uh[gn], ahg, 0, 0, 0);
            #pragma unroll
            for (int rg = 0; rg < 4; ++rg) {
                float z  = fast_sigmoid(az[rg] + bz[hf]);
                float r  = fast_sigmoid(ar[rg] + br[hf]);
                float hn = fast_tanh(axn[rg] + bnx[hf] + r * (ahg[rg] + bnh[hf]));
                hC[hf][rg] = z * hC[hf][rg] + (1.0f - z) * hn;
            }
        }

        __asm__ volatile("s_waitcnt lgkmcnt(0)" ::: "memory");
        #pragma unroll
        for (int hf = 0; hf < 2; ++hf)
            #pragma unroll
            for (int rg = 0; rg < 4; ++rg)
                T[(quad * 4 + rg) * 36 + hf * 16 + l15] = hC[hf][rg];
        __asm__ volatile("s_waitcnt lgkmcnt(0)" ::: "memory");
        {
            const float4* rd = (const float4*)(T + l15 * 36 + quad * 8);
            float4 v0 = rd[0], v1 = rd[1];
            hA[0]=v0.x; hA[1]=v0.y; hA[2]=v0.z; hA[3]=v0.w;
            hA[4]=v1.x; hA[5]=v1.y; hA[6]=v1.z; hA[7]=v1.w;
        }
        if (STORE_M) {
            float4* dst = (float4*)(m + (size_t)sl[l] * DIM + quad * 8);
            float4 v0 = { hA[0], hA[1], hA[2], hA[3] };
            float4 v1 = { hA[4], hA[5], hA[6], hA[7] };
            dst[0] = v0; dst[1] = v1;
        }
        if (l < PLEN - 1) split_bf16(hA, ah, al);
    }
    float4* ho = (float4*)(path_state + (size_t)p * DIM + quad * 8);
    float4 v0 = { hA[0], hA[1], hA[2], hA[3] };
    float4 v1 = { hA[4], hA[5], hA[6], hA[7] };
    ho[0] = v0; ho[1] = v1;
}

// ---------- fused aggregate + MFMA link GRU: wave = 16 links ----------
// aggregates m (slot-ordered, contiguous per link) directly into A-fragments,
// then one GRU step with resident Wl/Ul frags; stores link_state + ls hi/lo.
__global__ __launch_bounds__(256) void aglk_kernel(
    const int* __restrict__ row_start,
    const float* __restrict__ m,
    const unsigned short* __restrict__ lfr,
    const float* __restrict__ bl,
    float* __restrict__ link_state,
    unsigned short* __restrict__ ls_hi, unsigned short* __restrict__ ls_lo)
{
    __shared__ __align__(16) float T4[4][16 * 36];
    int t = threadIdx.x;
    int wave = t >> 6, lane = t & 63;
    int l15 = lane & 15, quad = lane >> 4;
    int lb = (blockIdx.x * 4 + wave) * 16;
    if (lb >= NLINKS) return;                   // NLINKS%16==0: full waves
    float* T = T4[wave];
    int link = lb + l15;

    // resident weight fragments
    bf16x8 Wh[6], Wlo[6], Uh[6], Ulo[6];
    {
        const uint4* base = (const uint4*)lfr;
        #pragma unroll
        for (int g = 0; g < 6; ++g) {
            FragCast a;
            a.u = base[0 * 384 + g * 64 + lane]; Wh[g]  = a.v;
            a.u = base[1 * 384 + g * 64 + lane]; Wlo[g] = a.v;
            a.u = base[2 * 384 + g * 64 + lane]; Uh[g]  = a.v;
            a.u = base[3 * 384 + g * 64 + lane]; Ulo[g] = a.v;
        }
    }
    float bz[2], br[2], bnx[2], bnh[2];
    #pragma unroll
    for (int hf = 0; hf < 2; ++hf) {
        int c = hf * 16 + l15;
        bz[hf]  = bl[c]      + bl[96 + c];
        br[hf]  = bl[32 + c] + bl[96 + 32 + c];
        bnx[hf] = bl[64 + c];
        bnh[hf] = bl[96 + 64 + c];
    }

    // aggregate: lane sums dims [quad*8, quad*8+8) over this link's m rows
    int s0 = row_start[link], s1 = row_start[link + 1];
    float x8[8] = {0.f,0.f,0.f,0.f,0.f,0.f,0.f,0.f};
    int i = s0;
    for (; i + 4 <= s1; i += 4) {
        #pragma unroll
        for (int u = 0; u < 4; ++u) {
            const float4* mr = (const float4*)(m + (size_t)(i + u) * DIM + quad * 8);
            float4 a = mr[0], b = mr[1];
            x8[0] += a.x; x8[1] += a.y; x8[2] += a.z; x8[3] += a.w;
            x8[4] += b.x; x8[5] += b.y; x8[6] += b.z; x8[7] += b.w;
        }
    }
    for (; i < s1; ++i) {
        const float4* mr = (const float4*)(m + (size_t)i * DIM + quad * 8);
        float4 a = mr[0], b = mr[1];
        x8[0] += a.x; x8[1] += a.y; x8[2] += a.z; x8[3] += a.w;
        x8[4] += b.x; x8[5] += b.y; x8[6] += b.z; x8[7] += b.w;
    }
    bf16x8 xh, xl;
    split_bf16(x8, xh, xl);

    // h: A-row load + C-layout via wave-private LDS
    float hA[8];
    {
        const float4* src = (const float4*)(link_state + (size_t)link * DIM + quad * 8);
        float4 v0 = src[0], v1 = src[1];
        hA[0]=v0.x; hA[1]=v0.y; hA[2]=v0.z; hA[3]=v0.w;
        hA[4]=v1.x; hA[5]=v1.y; hA[6]=v1.z; hA[7]=v1.w;
    }
    #pragma unroll
    for (int j = 0; j < 8; ++j) T[l15 * 36 + quad * 8 + j] = hA[j];
    __asm__ volatile("s_waitcnt lgkmcnt(0)" ::: "memory");
    float hC[2][4];
    #pragma unroll
    for (int hf = 0; hf < 2; ++hf)
        #pragma unroll
        for (int rg = 0; rg < 4; ++rg)
            hC[hf][rg] = T[(quad * 4 + rg) * 36 + hf * 16 + l15];
    bf16x8 ah, al;
    split_bf16(hA, ah, al);

    #pragma unroll
    for (int hf = 0; hf < 2; ++hf) {
        f32x4 az = {0.f,0.f,0.f,0.f}, ar = {0.f,0.f,0.f,0.f};
        f32x4 axn = {0.f,0.f,0.f,0.f}, ahg = {0.f,0.f,0.f,0.f};
        int gz = hf, gr = 2 + hf, gn = 4 + hf;
        az = __builtin_amdgcn_mfma_f32_16x16x32_bf16(xh, Wh[gz],  az, 0, 0, 0);
        az = __builtin_amdgcn_mfma_f32_16x16x32_bf16(xh, Wlo[gz], az, 0, 0, 0);
        az = __builtin_amdgcn_mfma_f32_16x16x32_bf16(xl, Wh[gz],  az, 0, 0, 0);
        az = __builtin_amdgcn_mfma_f32_16x16x32_bf16(ah, Uh[gz],  az, 0, 0, 0);
        az = __builtin_amdgcn_mfma_f32_16x16x32_bf16(ah, Ulo[gz], az, 0, 0, 0);
        az = __builtin_amdgcn_mfma_f32_16x16x32_bf16(al, Uh[gz],  az, 0, 0, 0);
        ar = __builtin_amdgcn_mfma_f32_16x16x32_bf16(xh, Wh[gr],  ar, 0, 0, 0);
        ar = __builtin_amdgcn_mfma_f32_16x16x32_bf16(xh, Wlo[gr], ar, 0, 0, 0);
        ar = __builtin_amdgcn_mfma_f32_16x16x32_bf16(xl, Wh[gr],  ar, 0, 0, 0);
        ar = __builtin_amdgcn_mfma_f32_16x16x32_bf16(ah, Uh[gr],  ar, 0, 0, 0);
        ar = __builtin_amdgcn_mfma_f32_16x16x32_bf16(ah, Ulo[gr], ar, 0, 0, 0);
        ar = __builtin_amdgcn_mfma_f32_16x16x32_bf16(al, Uh[gr],  ar, 0, 0, 0);
        axn = __builtin_amdgcn_mfma_f32_16x16x32_bf16(xh, Wh[gn],  axn, 0, 0, 0);
        axn = __builtin_amdgcn_mfma_f32_16x16x32_bf16(xh, Wlo[gn], axn, 0, 0, 0);
        axn = __builtin_amdgcn_mfma_f32_16x16x32_bf16(xl, Wh[gn],  axn, 0, 0, 0);
        ahg = __builtin_amdgcn_mfma_f32_16x16x32_bf16(ah, Uh[gn],  ahg, 0, 0, 0);
        ahg = __builtin_amdgcn_mfma_f32_16x16x32_bf16(ah, Ulo[gn], ahg, 0, 0, 0);
        ahg = __builtin_amdgcn_mfma_f32_16x16x32_bf16(al, Uh[gn],  ahg, 0, 0, 0);
        #pragma unroll
        for (int rg = 0; rg < 4; ++rg) {
            float z  = fast_sigmoid(az[rg] + bz[hf]);
            float r  = fast_sigmoid(ar[rg] + br[hf]);
            float hn = fast_tanh(axn[rg] + bnx[hf] + r * (ahg[rg] + bnh[hf]));
            hC[hf][rg] = z * hC[hf][rg] + (1.0f - z) * hn;
        }
    }

    // C -> A-row via LDS, store
    __asm__ volatile("s_waitcnt lgkmcnt(0)" ::: "memory");
    #pragma unroll
    for (int hf = 0; hf < 2; ++hf)
        #pragma unroll
        for (int rg = 0; rg < 4; ++rg)
            T[(quad * 4 + rg) * 36 + hf * 16 + l15] = hC[hf][rg];
    __asm__ volatile("s_waitcnt lgkmcnt(0)" ::: "memory");
    {
        const float4* rd = (const float4*)(T + l15 * 36 + quad * 8);
        float4 v0 = rd[0], v1 = rd[1];
        hA[0]=v0.x; hA[1]=v0.y; hA[2]=v0.z; hA[3]=v0.w;
        hA[4]=v1.x; hA[5]=v1.y; hA[6]=v1.z; hA[7]=v1.w;
    }
    float4* ho = (float4*)(link_state + (size_t)link * DIM + quad * 8);
    float4 v0 = { hA[0], hA[1], hA[2], hA[3] };
    float4 v1 = { hA[4], hA[5], hA[6], hA[7] };
    ho[0] = v0; ho[1] = v1;
    bf16x8 nh, nl;
    split_bf16(hA, nh, nl);
    FragCast ch, cl;
    ch.v = nh; cl.v = nl;
    *(uint4*)(ls_hi + (size_t)link * DIM + quad * 8) = ch.u;
    *(uint4*)(ls_lo + (size_t)link * DIM + quad * 8) = cl.u;
}

// ---------- MFMA readout: wave = 32 paths (2 tiles), h1 staged bf16 hi/lo ----
__global__ __launch_bounds__(128, 1) void readout_kernel(
    const float* __restrict__ path_state,
    const unsigned short* __restrict__ rfr,
    const float* __restrict__ Rb1, const float* __restrict__ Rb2,
    const float* __restrict__ R3,  const float* __restrict__ Rb3,
    float* __restrict__ out)
{
    __shared__ __align__(16) unsigned short Thi[2][32 * 264];   // 16.9 KB/wave
    __shared__ __align__(16) unsigned short Tlo[2][32 * 264];
    int t = threadIdx.x;
    int wave = t >> 6, lane = t & 63;
    int l15 = lane & 15, quad = lane >> 4;
    int p0 = (blockIdx.x * 2 + wave) * 32;
    if (p0 >= NP) return;
    unsigned short* TH = Thi[wave];
    unsigned short* TL = Tlo[wave];

    const uint4* r1h = (const uint4*)rfr;
    const uint4* r1l = r1h + 1024;
    const uint4* r2h = r1l + 1024;
    const uint4* r2l = r2h + 8192;

    // A0 fragments for both tiles
    bf16x8 a0h[2], a0l[2];
    #pragma unroll
    for (int tl = 0; tl < 2; ++tl) {
        int p = p0 + tl * 16 + l15;
        float h0[8];
        const float4* src = (const float4*)(path_state + (size_t)p * DIM + quad * 8);
        float4 v0 = src[0], v1 = src[1];
        h0[0]=v0.x; h0[1]=v0.y; h0[2]=v0.z; h0[3]=v0.w;
        h0[4]=v1.x; h0[5]=v1.y; h0[6]=v1.z; h0[7]=v1.w;
        split_bf16(h0, a0h[tl], a0l[tl]);
    }

    // layer 1: h1 = selu(h0 @ R1 + Rb1), stored hi/lo bf16 in LDS
    #pragma unroll 1
    for (int g = 0; g < 16; ++g) {
        FragCast bh, bl2;
        bh.u  = r1h[g * 64 + lane];
        bl2.u = r1l[g * 64 + lane];
        float rb = Rb1[g * 16 + l15];
        #pragma unroll
        for (int tl = 0; tl < 2; ++tl) {
            f32x4 c = {0.f,0.f,0.f,0.f};
            c = __builtin_amdgcn_mfma_f32_16x16x32_bf16(a0h[tl], bh.v,  c, 0, 0, 0);
            c = __builtin_amdgcn_mfma_f32_16x16x32_bf16(a0h[tl], bl2.v, c, 0, 0, 0);
            c = __builtin_amdgcn_mfma_f32_16x16x32_bf16(a0l[tl], bh.v,  c, 0, 0, 0);
            #pragma unroll
            for (int rg = 0; rg < 4; ++rg) {
                float v = seluf(c[rg] + rb);
                unsigned short vh = f2bf(v);
                unsigned short vl = f2bf(v - bf2f(vh));
                int idx = (tl * 16 + quad * 4 + rg) * 264 + g * 16 + l15;
                TH[idx] = vh;
                TL[idx] = vl;
            }
        }
    }
    __asm__ volatile("s_waitcnt lgkmcnt(0)" ::: "memory");

    // h1 A-fragments (bf16 direct, no split VALU)
    bf16x8 h1h[2][8], h1l[2][8];
    #pragma unroll
    for (int tl = 0; tl < 2; ++tl)
        #pragma unroll
        for (int c = 0; c < 8; ++c) {
            int idx = (tl * 16 + l15) * 264 + c * 32 + quad * 8;
            FragCast a, b;
            a.u = *(const uint4*)(TH + idx);
            b.u = *(const uint4*)(TL + idx);
            h1h[tl][c] = a.v;
            h1l[tl][c] = b.v;
        }

    // layer 2 + 3
    float s[2][4] = {{0.f,0.f,0.f,0.f},{0.f,0.f,0.f,0.f}};
    #pragma unroll 1
    for (int g = 0; g < 16; ++g) {
        f32x4 acc0 = {0.f,0.f,0.f,0.f}, acc1 = {0.f,0.f,0.f,0.f};
        #pragma unroll 2
        for (int c = 0; c < 8; ++c) {
            FragCast bh, bl2;
            bh.u  = r2h[(c * 16 + g) * 64 + lane];
            bl2.u = r2l[(c * 16 + g) * 64 + lane];
            acc0 = __builtin_amdgcn_mfma_f32_16x16x32_bf16(h1h[0][c], bh.v,  acc0, 0, 0, 0);
            acc0 = __builtin_amdgcn_mfma_f32_16x16x32_bf16(h1h[0][c], bl2.v, acc0, 0, 0, 0);
            acc0 = __builtin_amdgcn_mfma_f32_16x16x32_bf16(h1l[0][c], bh.v,  acc0, 0, 0, 0);
            acc1 = __builtin_amdgcn_mfma_f32_16x16x32_bf16(h1h[1][c], bh.v,  acc1, 0, 0, 0);
            acc1 = __builtin_amdgcn_mfma_f32_16x16x32_bf16(h1h[1][c], bl2.v, acc1, 0, 0, 0);
            acc1 = __builtin_amdgcn_mfma_f32_16x16x32_bf16(h1l[1][c], bh.v,  acc1, 0, 0, 0);
        }
        float rb  = Rb2[g * 16 + l15];
        float r3v = R3[g * 16 + l15];
        #pragma unroll
        for (int rg = 0; rg < 4; ++rg) {
            s[0][rg] += seluf(acc0[rg] + rb) * r3v;
            s[1][rg] += seluf(acc1[rg] + rb) * r3v;
        }
    }
    #pragma unroll
    for (int tl = 0; tl < 2; ++tl)
        #pragma unroll
        for (int rg = 0; rg < 4; ++rg) {
            s[tl][rg] += __shfl_xor(s[tl][rg], 1);
            s[tl][rg] += __shfl_xor(s[tl][rg], 2);
            s[tl][rg] += __shfl_xor(s[tl][rg], 4);
            s[tl][rg] += __shfl_xor(s[tl][rg], 8);
        }
    if (l15 == 0) {
        float rb3 = Rb3[0];
        #pragma unroll
        for (int tl = 0; tl < 2; ++tl)
            #pragma unroll
            for (int rg = 0; rg < 4; ++rg)
                out[p0 + tl * 16 + quad * 4 + rg] = s[tl][rg] + rb3;
    }
}

extern "C" void kernel_launch(void* const* d_in, const int* in_sizes, int n_in,
                              void* d_out, int out_size, void* d_ws, size_t ws_size,
                              hipStream_t stream)
{
    const int*   links = (const int*)d_in[0];
    const float* cap = (const float*)d_in[3];
    const float* pol = (const float*)d_in[4];
    const float* wts = (const float*)d_in[5];
    const float* bw  = (const float*)d_in[6];
    const float* tos = (const float*)d_in[7];
    const float* pk  = (const float*)d_in[8];
    const float* avg = (const float*)d_in[9];
    const float* Wp  = (const float*)d_in[10];
    const float* Up  = (const float*)d_in[11];
    const float* bp  = (const float*)d_in[12];
    const float* Wl  = (const float*)d_in[13];
    const float* Ul  = (const float*)d_in[14];
    const float* bl  = (const float*)d_in[15];
    const float* R1  = (const float*)d_in[16];
    const float* Rb1 = (const float*)d_in[17];
    const float* R2  = (const float*)d_in[18];
    const float* Rb2 = (const float*)d_in[19];
    const float* R3  = (const float*)d_in[20];
    const float* Rb3 = (const float*)d_in[21];

    char* w = (char*)d_ws;
    size_t off = 0;
    auto alloc = [&](size_t bytes) {
        char* p = w + off;
        off += (bytes + 255) & ~(size_t)255;
        return p;
    };
    float*          path_state = (float*)alloc((size_t)NP * DIM * 4);
    float*          link_state = (float*)alloc((size_t)NLINKS * DIM * 4);
    float*          m          = (float*)alloc((size_t)E_TOT * DIM * 4);
    unsigned short* ls_hi      = (unsigned short*)alloc((size_t)NLINKS * DIM * 2);
    unsigned short* ls_lo      = (unsigned short*)alloc((size_t)NLINKS * DIM * 2);
    unsigned short* wfr        = (unsigned short*)alloc(4 * 3072 * 2);
    unsigned short* lfr        = (unsigned short*)alloc(4 * 3072 * 2);
    unsigned short* rfr        = (unsigned short*)alloc((size_t)(8192 + 65536) * 2 * 2);
    int*            cnt        = (int*)alloc((size_t)NLINKS * 4);
    int*            row_start  = (int*)alloc((size_t)(NLINKS + 1) * 4);
    int*            cursor     = (int*)alloc((size_t)NLINKS * 4);
    int*            slot       = (int*)alloc((size_t)E_TOT * 4);

    init_kernel<<<(NP + 255) / 256, 256, 0, stream>>>(cap, pol, wts, bw, tos, pk, avg,
                                                      link_state, path_state, ls_hi, ls_lo);
    hipMemsetAsync(cnt, 0, (size_t)NLINKS * 4, stream);
    csr_count  <<<(E_TOT + 255) / 256, 256, 0, stream>>>(links, cnt);
    csr_scan   <<<1, 256, 0, stream>>>(cnt, row_start, cursor);
    csr_scatter<<<(E_TOT + 255) / 256, 256, 0, stream>>>(links, cursor, slot);
    wprep_kernel<<<12, 256, 0, stream>>>(Wp, Up, wfr);
    wprep_kernel<<<12, 256, 0, stream>>>(Wl, Ul, lfr);
    rprep_kernel<<<(8192 + 65536 + 255) / 256, 256, 0, stream>>>(R1, R2, rfr);

    const int PGRID = (NP / 16 + 3) / 4;
    const int LGRID = (NLINKS / 16 + 3) / 4;
    for (int it = 0; it < TITERS; ++it) {
        if (it < TITERS - 1) {
            path_kernel<true><<<PGRID, 256, 0, stream>>>(links, wfr, bp, ls_hi, ls_lo,
                                                         slot, path_state, m);
            aglk_kernel<<<LGRID, 256, 0, stream>>>(row_start, m, lfr, bl,
                                                   link_state, ls_hi, ls_lo);
        } else {
            path_kernel<false><<<PGRID, 256, 0, stream>>>(links, wfr, bp, ls_hi, ls_lo,
                                                          slot, path_state, m);
        }
    }
    readout_kernel<<<(NP / 32 + 1) / 2, 128, 0, stream>>>(path_state, rfr, Rb1, Rb2,
                                                          R3, Rb3, (float*)d_out);
}

// Round 14
// 845.990 us; speedup vs baseline: 1.3187x; 1.3187x over previous
//
#include <hip/hip_runtime.h>
#include <hip/hip_bf16.h>

#define NP     100000   // n_paths
#define PLEN   5        // path length
#define NLINKS 10000    // n_links
#define DIM    32       // state dim
#define TITERS 8        // message passing iterations
#define E_TOT  (NP * PLEN)

using bf16x8 = __attribute__((ext_vector_type(8))) short;
using f32x4  = __attribute__((ext_vector_type(4))) float;
union FragCast { uint4 u; bf16x8 v; };

// ---------- helpers ----------
__device__ __forceinline__ float fast_sigmoid(float v) {
    return 1.0f / (1.0f + __expf(-v));
}
__device__ __forceinline__ float fast_tanh(float v) {
    float e = __expf(-2.0f * fabsf(v));
    float t = (1.0f - e) / (1.0f + e);
    return v >= 0.0f ? t : -t;
}
__device__ __forceinline__ float seluf(float v) {
    const float sc = 1.0507009873554805f;
    const float al = 1.6732632423543772f;
    return v > 0.0f ? sc * v : sc * al * (__expf(v) - 1.0f);
}
__device__ __forceinline__ unsigned short f2bf(float f) {
    union { float f; unsigned u; } c; c.f = f;
    unsigned u = c.u;
    return (unsigned short)((u + 0x7fffu + ((u >> 16) & 1u)) >> 16);
}
__device__ __forceinline__ float bf2f(unsigned short b) {
    union { unsigned u; float f; } c; c.u = ((unsigned)b) << 16;
    return c.f;
}
__device__ __forceinline__ void split_bf16(const float (&v)[8], bf16x8& hi, bf16x8& lo) {
    unsigned uh[4], ul[4];
    #pragma unroll
    for (int i = 0; i < 4; ++i) {
        unsigned short h0 = f2bf(v[2*i]),   h1 = f2bf(v[2*i+1]);
        float r0 = v[2*i] - bf2f(h0),       r1 = v[2*i+1] - bf2f(h1);
        unsigned short l0 = f2bf(r0),       l1 = f2bf(r1);
        uh[i] = (unsigned)h0 | ((unsigned)h1 << 16);
        ul[i] = (unsigned)l0 | ((unsigned)l1 << 16);
    }
    FragCast ch, cl;
    ch.u.x = uh[0]; ch.u.y = uh[1]; ch.u.z = uh[2]; ch.u.w = uh[3];
    cl.u.x = ul[0]; cl.u.y = ul[1]; cl.u.z = ul[2]; cl.u.w = ul[3];
    hi = ch.v; lo = cl.v;
}

// ---------- init (also writes hi/lo split of initial link_state) ----------
__global__ __launch_bounds__(256) void init_kernel(
    const float* __restrict__ cap, const float* __restrict__ pol, const float* __restrict__ wts,
    const float* __restrict__ bw,  const float* __restrict__ tos,
    const float* __restrict__ pk,  const float* __restrict__ avg,
    float* __restrict__ link_state, float* __restrict__ path_state,
    unsigned short* __restrict__ ls_hi, unsigned short* __restrict__ ls_lo)
{
    int i = blockIdx.x * 256 + threadIdx.x;
    if (i < NLINKS) {
        float row[DIM];
        #pragma unroll
        for (int c = 0; c < DIM; ++c) row[c] = 0.0f;
        row[0] = cap[i]; row[1] = pol[i]; row[2] = wts[i];
        float4* o = (float4*)(link_state + (size_t)i * DIM);
        #pragma unroll
        for (int c = 0; c < 8; ++c) {
            float4 v = { row[4*c], row[4*c+1], row[4*c+2], row[4*c+3] };
            o[c] = v;
        }
        unsigned ush[16], usl[16];
        #pragma unroll
        for (int c = 0; c < 16; ++c) {
            unsigned short h0 = f2bf(row[2*c]), h1 = f2bf(row[2*c+1]);
            unsigned short l0 = f2bf(row[2*c] - bf2f(h0));
            unsigned short l1 = f2bf(row[2*c+1] - bf2f(h1));
            ush[c] = (unsigned)h0 | ((unsigned)h1 << 16);
            usl[c] = (unsigned)l0 | ((unsigned)l1 << 16);
        }
        uint4* oh = (uint4*)(ls_hi + (size_t)i * DIM);
        uint4* ol = (uint4*)(ls_lo + (size_t)i * DIM);
        #pragma unroll
        for (int q = 0; q < 4; ++q) {
            uint4 vh = { ush[4*q], ush[4*q+1], ush[4*q+2], ush[4*q+3] };
            uint4 vl = { usl[4*q], usl[4*q+1], usl[4*q+2], usl[4*q+3] };
            oh[q] = vh; ol[q] = vl;
        }
    }
    if (i < NP) {
        float row[DIM];
        #pragma unroll
        for (int c = 0; c < DIM; ++c) row[c] = 0.0f;
        row[0] = bw[i]; row[1] = tos[i]; row[2] = pk[i]; row[3] = avg[i];
        float4* o = (float4*)(path_state + (size_t)i * DIM);
        #pragma unroll
        for (int c = 0; c < 8; ++c) {
            float4 v = { row[4*c], row[4*c+1], row[4*c+2], row[4*c+3] };
            o[c] = v;
        }
    }
}

// ---------- CSR build ----------
__global__ __launch_bounds__(256) void csr_count(const int* __restrict__ links,
                                                 int* __restrict__ cnt)
{
    int e = blockIdx.x * 256 + threadIdx.x;
    if (e < E_TOT) atomicAdd(&cnt[links[e]], 1);
}

__global__ __launch_bounds__(256) void csr_scan(const int* __restrict__ cnt,
                                                int* __restrict__ row_start,
                                                int* __restrict__ cursor)
{
    __shared__ int s[256];
    int t = threadIdx.x;
    int carry = 0;
    for (int base = 0; base < NLINKS; base += 256) {
        int i = base + t;
        int v = (i < NLINKS) ? cnt[i] : 0;
        s[t] = v;
        __syncthreads();
        for (int off = 1; off < 256; off <<= 1) {
            int tv = (t >= off) ? s[t - off] : 0;
            __syncthreads();
            s[t] += tv;
            __syncthreads();
        }
        int excl = s[t] - v;
        if (i < NLINKS) { row_start[i] = carry + excl; cursor[i] = carry + excl; }
        int tot = s[255];
        __syncthreads();
        carry += tot;
    }
    if (t == 0) row_start[NLINKS] = carry;
}

__global__ __launch_bounds__(256) void csr_scatter(const int* __restrict__ links,
                                                   int* __restrict__ cursor,
                                                   int* __restrict__ slot)
{
    int e = blockIdx.x * 256 + threadIdx.x;
    if (e < E_TOT) slot[e] = atomicAdd(&cursor[links[e]], 1);
}

// ---------- once per launch: GRU weights -> MFMA B-frags (hi/lo) ----------
__global__ __launch_bounds__(256) void wprep_kernel(const float* __restrict__ W,
                                                    const float* __restrict__ U,
                                                    unsigned short* __restrict__ ofr)
{
    int idx = blockIdx.x * 256 + threadIdx.x;
    if (idx >= 6 * 64 * 8) return;
    int j = idx & 7, lane = (idx >> 3) & 63, g = idx >> 9;
    int k = (lane >> 4) * 8 + j;
    int n = g * 16 + (lane & 15);
    float w = W[k * 96 + n];
    float u = U[k * 96 + n];
    unsigned short whi = f2bf(w); unsigned short wlo = f2bf(w - bf2f(whi));
    unsigned short uhi = f2bf(u); unsigned short ulo = f2bf(u - bf2f(uhi));
    ofr[0 * 3072 + idx] = whi;
    ofr[1 * 3072 + idx] = wlo;
    ofr[2 * 3072 + idx] = uhi;
    ofr[3 * 3072 + idx] = ulo;
}

// ---------- once per launch: readout R1/R2 -> MFMA B-frags (hi/lo) ----------
__global__ __launch_bounds__(256) void rprep_kernel(const float* __restrict__ R1,
                                                    const float* __restrict__ R2,
                                                    unsigned short* __restrict__ rfr)
{
    int idx = blockIdx.x * 256 + threadIdx.x;
    if (idx >= 8192 + 65536) return;
    if (idx < 8192) {
        int j = idx & 7, lane = (idx >> 3) & 63, g = idx >> 9;
        int k = (lane >> 4) * 8 + j;
        int n = g * 16 + (lane & 15);
        float v = R1[k * 256 + n];
        unsigned short hi = f2bf(v);
        rfr[idx] = hi;
        rfr[8192 + idx] = f2bf(v - bf2f(hi));
    } else {
        int idx2 = idx - 8192;
        int j = idx2 & 7, lane = (idx2 >> 3) & 63, tile = idx2 >> 9;
        int c = tile >> 4, g = tile & 15;
        int k = c * 32 + (lane >> 4) * 8 + j;
        int n = g * 16 + (lane & 15);
        float v = R2[k * 256 + n];
        unsigned short hi = f2bf(v);
        rfr[16384 + idx2] = hi;
        rfr[16384 + 65536 + idx2] = f2bf(v - bf2f(hi));
    }
}

// ---------- MFMA path GRU (R11/R12-proven, unchanged) ----------
template <bool STORE_M>
__global__ __launch_bounds__(256) void path_kernel(
    const int*   __restrict__ links,
    const unsigned short* __restrict__ wfr,
    const float* __restrict__ bp,
    const unsigned short* __restrict__ ls_hi,
    const unsigned short* __restrict__ ls_lo,
    const int*   __restrict__ slot,
    float* __restrict__ path_state,
    float* __restrict__ m)
{
    __shared__ __align__(16) float T4[4][16 * 36];
    int t = threadIdx.x;
    int wave = t >> 6, lane = t & 63;
    int l15 = lane & 15, quad = lane >> 4;
    int p0 = (blockIdx.x * 4 + wave) * 16;
    if (p0 >= NP) return;
    float* T = T4[wave];
    int p = p0 + l15;

    int lk[PLEN];
    #pragma unroll
    for (int l = 0; l < PLEN; ++l) lk[l] = links[p * PLEN + l];
    bf16x8 pxh[PLEN], pxl[PLEN];
    #pragma unroll
    for (int l = 0; l < PLEN; ++l) {
        FragCast ch, cl;
        ch.u = *(const uint4*)(ls_hi + (size_t)lk[l] * DIM + quad * 8);
        cl.u = *(const uint4*)(ls_lo + (size_t)lk[l] * DIM + quad * 8);
        pxh[l] = ch.v; pxl[l] = cl.v;
    }
    int sl[PLEN];
    if (STORE_M) {
        #pragma unroll
        for (int l = 0; l < PLEN; ++l) sl[l] = slot[p * PLEN + l];
    }

    bf16x8 Wh[6], Wl[6], Uh[6], Ul[6];
    {
        const uint4* base = (const uint4*)wfr;
        #pragma unroll
        for (int g = 0; g < 6; ++g) {
            FragCast a;
            a.u = base[0 * 384 + g * 64 + lane]; Wh[g] = a.v;
            a.u = base[1 * 384 + g * 64 + lane]; Wl[g] = a.v;
            a.u = base[2 * 384 + g * 64 + lane]; Uh[g] = a.v;
            a.u = base[3 * 384 + g * 64 + lane]; Ul[g] = a.v;
        }
    }
    float bz[2], br[2], bnx[2], bnh[2];
    #pragma unroll
    for (int hf = 0; hf < 2; ++hf) {
        int c = hf * 16 + l15;
        bz[hf]  = bp[c]      + bp[96 + c];
        br[hf]  = bp[32 + c] + bp[96 + 32 + c];
        bnx[hf] = bp[64 + c];
        bnh[hf] = bp[96 + 64 + c];
    }

    float hA[8];
    {
        const float4* src = (const float4*)(path_state + (size_t)p * DIM + quad * 8);
        float4 v0 = src[0], v1 = src[1];
        hA[0]=v0.x; hA[1]=v0.y; hA[2]=v0.z; hA[3]=v0.w;
        hA[4]=v1.x; hA[5]=v1.y; hA[6]=v1.z; hA[7]=v1.w;
    }
    #pragma unroll
    for (int j = 0; j < 8; ++j) T[l15 * 36 + quad * 8 + j] = hA[j];
    __asm__ volatile("s_waitcnt lgkmcnt(0)" ::: "memory");
    float hC[2][4];
    #pragma unroll
    for (int hf = 0; hf < 2; ++hf)
        #pragma unroll
        for (int rg = 0; rg < 4; ++rg)
            hC[hf][rg] = T[(quad * 4 + rg) * 36 + hf * 16 + l15];

    bf16x8 ah, al;
    split_bf16(hA, ah, al);

    #pragma unroll
    for (int l = 0; l < PLEN; ++l) {
        bf16x8 xh = pxh[l], xl = pxl[l];
        #pragma unroll
        for (int hf = 0; hf < 2; ++hf) {
            f32x4 az = {0.f,0.f,0.f,0.f}, ar = {0.f,0.f,0.f,0.f};
            f32x4 axn = {0.f,0.f,0.f,0.f}, ahg = {0.f,0.f,0.f,0.f};
            int gz = hf, gr = 2 + hf, gn = 4 + hf;
            az = __builtin_amdgcn_mfma_f32_16x16x32_bf16(xh, Wh[gz], az, 0, 0, 0);
            az = __builtin_amdgcn_mfma_f32_16x16x32_bf16(xh, Wl[gz], az, 0, 0, 0);
            az = __builtin_amdgcn_mfma_f32_16x16x32_bf16(xl, Wh[gz], az, 0, 0, 0);
            az = __builtin_amdgcn_mfma_f32_16x16x32_bf16(ah, Uh[gz], az, 0, 0, 0);
            az = __builtin_amdgcn_mfma_f32_16x16x32_bf16(ah, Ul[gz], az, 0, 0, 0);
            az = __builtin_amdgcn_mfma_f32_16x16x32_bf16(al, Uh[gz], az, 0, 0, 0);
            ar = __builtin_amdgcn_mfma_f32_16x16x32_bf16(xh, Wh[gr], ar, 0, 0, 0);
            ar = __builtin_amdgcn_mfma_f32_16x16x32_bf16(xh, Wl[gr], ar, 0, 0, 0);
            ar = __builtin_amdgcn_mfma_f32_16x16x32_bf16(xl, Wh[gr], ar, 0, 0, 0);
            ar = __builtin_amdgcn_mfma_f32_16x16x32_bf16(ah, Uh[gr], ar, 0, 0, 0);
            ar = __builtin_amdgcn_mfma_f32_16x16x32_bf16(ah, Ul[gr], ar, 0, 0, 0);
            ar = __builtin_amdgcn_mfma_f32_16x16x32_bf16(al, Uh[gr], ar, 0, 0, 0);
            axn = __builtin_amdgcn_mfma_f32_16x16x32_bf16(xh, Wh[gn], axn, 0, 0, 0);
            axn = __builtin_amdgcn_mfma_f32_16x16x32_bf16(xh, Wl[gn], axn, 0, 0, 0);
            axn = __builtin_amdgcn_mfma_f32_16x16x32_bf16(xl, Wh[gn], axn, 0, 0, 0);
            ahg = __builtin_amdgcn_mfma_f32_16x16x32_bf16(ah, Uh[gn], ahg, 0, 0, 0);
            ahg = __builtin_amdgcn_mfma_f32_16x16x32_bf16(ah, Ul[gn], ahg, 0, 0, 0);
            ahg = __builtin_amdgcn_mfma_f32_16x16x32_bf16(al, Uh[gn], ahg, 0, 0, 0);
            #pragma unroll
            for (int rg = 0; rg < 4; ++rg) {
                float z  = fast_sigmoid(az[rg] + bz[hf]);
                float r  = fast_sigmoid(ar[rg] + br[hf]);
                float hn = fast_tanh(axn[rg] + bnx[hf] + r * (ahg[rg] + bnh[hf]));
                hC[hf][rg] = z * hC[hf][rg] + (1.0f - z) * hn;
            }
        }

        __asm__ volatile("s_waitcnt lgkmcnt(0)" ::: "memory");
        #pragma unroll
        for (int hf = 0; hf < 2; ++hf)
            #pragma unroll
            for (int rg = 0; rg < 4; ++rg)
                T[(quad * 4 + rg) * 36 + hf * 16 + l15] = hC[hf][rg];
        __asm__ volatile("s_waitcnt lgkmcnt(0)" ::: "memory");
        {
            const float4* rd = (const float4*)(T + l15 * 36 + quad * 8);
            float4 v0 = rd[0], v1 = rd[1];
            hA[0]=v0.x; hA[1]=v0.y; hA[2]=v0.z; hA[3]=v0.w;
            hA[4]=v1.x; hA[5]=v1.y; hA[6]=v1.z; hA[7]=v1.w;
        }
        if (STORE_M) {
            float4* dst = (float4*)(m + (size_t)sl[l] * DIM + quad * 8);
            float4 v0 = { hA[0], hA[1], hA[2], hA[3] };
            float4 v1 = { hA[4], hA[5], hA[6], hA[7] };
            dst[0] = v0; dst[1] = v1;
        }
        if (l < PLEN - 1) split_bf16(hA, ah, al);
    }
    float4* ho = (float4*)(path_state + (size_t)p * DIM + quad * 8);
    float4 v0 = { hA[0], hA[1], hA[2], hA[3] };
    float4 v1 = { hA[4], hA[5], hA[6], hA[7] };
    ho[0] = v0; ho[1] = v1;
}

// ---------- fused aggregate + MFMA link GRU (R13-verified, unchanged) ----------
__global__ __launch_bounds__(256) void aglk_kernel(
    const int* __restrict__ row_start,
    const float* __restrict__ m,
    const unsigned short* __restrict__ lfr,
    const float* __restrict__ bl,
    float* __restrict__ link_state,
    unsigned short* __restrict__ ls_hi, unsigned short* __restrict__ ls_lo)
{
    __shared__ __align__(16) float T4[4][16 * 36];
    int t = threadIdx.x;
    int wave = t >> 6, lane = t & 63;
    int l15 = lane & 15, quad = lane >> 4;
    int lb = (blockIdx.x * 4 + wave) * 16;
    if (lb >= NLINKS) return;
    float* T = T4[wave];
    int link = lb + l15;

    bf16x8 Wh[6], Wlo[6], Uh[6], Ulo[6];
    {
        const uint4* base = (const uint4*)lfr;
        #pragma unroll
        for (int g = 0; g < 6; ++g) {
            FragCast a;
            a.u = base[0 * 384 + g * 64 + lane]; Wh[g]  = a.v;
            a.u = base[1 * 384 + g * 64 + lane]; Wlo[g] = a.v;
            a.u = base[2 * 384 + g * 64 + lane]; Uh[g]  = a.v;
            a.u = base[3 * 384 + g * 64 + lane]; Ulo[g] = a.v;
        }
    }
    float bz[2], br[2], bnx[2], bnh[2];
    #pragma unroll
    for (int hf = 0; hf < 2; ++hf) {
        int c = hf * 16 + l15;
        bz[hf]  = bl[c]      + bl[96 + c];
        br[hf]  = bl[32 + c] + bl[96 + 32 + c];
        bnx[hf] = bl[64 + c];
        bnh[hf] = bl[96 + 64 + c];
    }

    int s0 = row_start[link], s1 = row_start[link + 1];
    float x8[8] = {0.f,0.f,0.f,0.f,0.f,0.f,0.f,0.f};
    int i = s0;
    for (; i + 4 <= s1; i += 4) {
        #pragma unroll
        for (int u = 0; u < 4; ++u) {
            const float4* mr = (const float4*)(m + (size_t)(i + u) * DIM + quad * 8);
            float4 a = mr[0], b = mr[1];
            x8[0] += a.x; x8[1] += a.y; x8[2] += a.z; x8[3] += a.w;
            x8[4] += b.x; x8[5] += b.y; x8[6] += b.z; x8[7] += b.w;
        }
    }
    for (; i < s1; ++i) {
        const float4* mr = (const float4*)(m + (size_t)i * DIM + quad * 8);
        float4 a = mr[0], b = mr[1];
        x8[0] += a.x; x8[1] += a.y; x8[2] += a.z; x8[3] += a.w;
        x8[4] += b.x; x8[5] += b.y; x8[6] += b.z; x8[7] += b.w;
    }
    bf16x8 xh, xl;
    split_bf16(x8, xh, xl);

    float hA[8];
    {
        const float4* src = (const float4*)(link_state + (size_t)link * DIM + quad * 8);
        float4 v0 = src[0], v1 = src[1];
        hA[0]=v0.x; hA[1]=v0.y; hA[2]=v0.z; hA[3]=v0.w;
        hA[4]=v1.x; hA[5]=v1.y; hA[6]=v1.z; hA[7]=v1.w;
    }
    #pragma unroll
    for (int j = 0; j < 8; ++j) T[l15 * 36 + quad * 8 + j] = hA[j];
    __asm__ volatile("s_waitcnt lgkmcnt(0)" ::: "memory");
    float hC[2][4];
    #pragma unroll
    for (int hf = 0; hf < 2; ++hf)
        #pragma unroll
        for (int rg = 0; rg < 4; ++rg)
            hC[hf][rg] = T[(quad * 4 + rg) * 36 + hf * 16 + l15];
    bf16x8 ah, al;
    split_bf16(hA, ah, al);

    #pragma unroll
    for (int hf = 0; hf < 2; ++hf) {
        f32x4 az = {0.f,0.f,0.f,0.f}, ar = {0.f,0.f,0.f,0.f};
        f32x4 axn = {0.f,0.f,0.f,0.f}, ahg = {0.f,0.f,0.f,0.f};
        int gz = hf, gr = 2 + hf, gn = 4 + hf;
        az = __builtin_amdgcn_mfma_f32_16x16x32_bf16(xh, Wh[gz],  az, 0, 0, 0);
        az = __builtin_amdgcn_mfma_f32_16x16x32_bf16(xh, Wlo[gz], az, 0, 0, 0);
        az = __builtin_amdgcn_mfma_f32_16x16x32_bf16(xl, Wh[gz],  az, 0, 0, 0);
        az = __builtin_amdgcn_mfma_f32_16x16x32_bf16(ah, Uh[gz],  az, 0, 0, 0);
        az = __builtin_amdgcn_mfma_f32_16x16x32_bf16(ah, Ulo[gz], az, 0, 0, 0);
        az = __builtin_amdgcn_mfma_f32_16x16x32_bf16(al, Uh[gz],  az, 0, 0, 0);
        ar = __builtin_amdgcn_mfma_f32_16x16x32_bf16(xh, Wh[gr],  ar, 0, 0, 0);
        ar = __builtin_amdgcn_mfma_f32_16x16x32_bf16(xh, Wlo[gr], ar, 0, 0, 0);
        ar = __builtin_amdgcn_mfma_f32_16x16x32_bf16(xl, Wh[gr],  ar, 0, 0, 0);
        ar = __builtin_amdgcn_mfma_f32_16x16x32_bf16(ah, Uh[gr],  ar, 0, 0, 0);
        ar = __builtin_amdgcn_mfma_f32_16x16x32_bf16(ah, Ulo[gr], ar, 0, 0, 0);
        ar = __builtin_amdgcn_mfma_f32_16x16x32_bf16(al, Uh[gr],  ar, 0, 0, 0);
        axn = __builtin_amdgcn_mfma_f32_16x16x32_bf16(xh, Wh[gn],  axn, 0, 0, 0);
        axn = __builtin_amdgcn_mfma_f32_16x16x32_bf16(xh, Wlo[gn], axn, 0, 0, 0);
        axn = __builtin_amdgcn_mfma_f32_16x16x32_bf16(xl, Wh[gn],  axn, 0, 0, 0);
        ahg = __builtin_amdgcn_mfma_f32_16x16x32_bf16(ah, Uh[gn],  ahg, 0, 0, 0);
        ahg = __builtin_amdgcn_mfma_f32_16x16x32_bf16(ah, Ulo[gn], ahg, 0, 0, 0);
        ahg = __builtin_amdgcn_mfma_f32_16x16x32_bf16(al, Uh[gn],  ahg, 0, 0, 0);
        #pragma unroll
        for (int rg = 0; rg < 4; ++rg) {
            float z  = fast_sigmoid(az[rg] + bz[hf]);
            float r  = fast_sigmoid(ar[rg] + br[hf]);
            float hn = fast_tanh(axn[rg] + bnx[hf] + r * (ahg[rg] + bnh[hf]));
            hC[hf][rg] = z * hC[hf][rg] + (1.0f - z) * hn;
        }
    }

    __asm__ volatile("s_waitcnt lgkmcnt(0)" ::: "memory");
    #pragma unroll
    for (int hf = 0; hf < 2; ++hf)
        #pragma unroll
        for (int rg = 0; rg < 4; ++rg)
            T[(quad * 4 + rg) * 36 + hf * 16 + l15] = hC[hf][rg];
    __asm__ volatile("s_waitcnt lgkmcnt(0)" ::: "memory");
    {
        const float4* rd = (const float4*)(T + l15 * 36 + quad * 8);
        float4 v0 = rd[0], v1 = rd[1];
        hA[0]=v0.x; hA[1]=v0.y; hA[2]=v0.z; hA[3]=v0.w;
        hA[4]=v1.x; hA[5]=v1.y; hA[6]=v1.z; hA[7]=v1.w;
    }
    float4* ho = (float4*)(link_state + (size_t)link * DIM + quad * 8);
    float4 v0 = { hA[0], hA[1], hA[2], hA[3] };
    float4 v1 = { hA[4], hA[5], hA[6], hA[7] };
    ho[0] = v0; ho[1] = v1;
    bf16x8 nh, nl;
    split_bf16(hA, nh, nl);
    FragCast ch, cl;
    ch.v = nh; cl.v = nl;
    *(uint4*)(ls_hi + (size_t)link * DIM + quad * 8) = ch.u;
    *(uint4*)(ls_lo + (size_t)link * DIM + quad * 8) = cl.u;
}

// ---------- MFMA readout (R12-proven single-tile version) ----------
__global__ __launch_bounds__(128, 1) void readout_kernel(
    const float* __restrict__ path_state,
    const unsigned short* __restrict__ rfr,
    const float* __restrict__ Rb1, const float* __restrict__ Rb2,
    const float* __restrict__ R3,  const float* __restrict__ Rb3,
    float* __restrict__ out)
{
    __shared__ __align__(16) float T2[2][16 * 260];   // 33.3 KB
    int t = threadIdx.x;
    int wave = t >> 6, lane = t & 63;
    int l15 = lane & 15, quad = lane >> 4;
    int p0 = (blockIdx.x * 2 + wave) * 16;
    if (p0 >= NP) return;
    float* T = T2[wave];
    int p = p0 + l15;

    const uint4* r1h = (const uint4*)rfr;
    const uint4* r1l = r1h + 1024;
    const uint4* r2h = r1l + 1024;
    const uint4* r2l = r2h + 8192;

    float h0[8];
    {
        const float4* src = (const float4*)(path_state + (size_t)p * DIM + quad * 8);
        float4 v0 = src[0], v1 = src[1];
        h0[0]=v0.x; h0[1]=v0.y; h0[2]=v0.z; h0[3]=v0.w;
        h0[4]=v1.x; h0[5]=v1.y; h0[6]=v1.z; h0[7]=v1.w;
    }
    bf16x8 a0h, a0l;
    split_bf16(h0, a0h, a0l);
    #pragma unroll 1
    for (int g = 0; g < 16; ++g) {
        FragCast bh, bl2;
        bh.u  = r1h[g * 64 + lane];
        bl2.u = r1l[g * 64 + lane];
        f32x4 c = {0.f,0.f,0.f,0.f};
        c = __builtin_amdgcn_mfma_f32_16x16x32_bf16(a0h, bh.v,  c, 0, 0, 0);
        c = __builtin_amdgcn_mfma_f32_16x16x32_bf16(a0h, bl2.v, c, 0, 0, 0);
        c = __builtin_amdgcn_mfma_f32_16x16x32_bf16(a0l, bh.v,  c, 0, 0, 0);
        float rb = Rb1[g * 16 + l15];
        #pragma unroll
        for (int rg = 0; rg < 4; ++rg)
            T[(quad * 4 + rg) * 260 + g * 16 + l15] = seluf(c[rg] + rb);
    }
    __asm__ volatile("s_waitcnt lgkmcnt(0)" ::: "memory");

    bf16x8 h1h[8], h1l[8];
    #pragma unroll
    for (int c = 0; c < 8; ++c) {
        float hv[8];
        const float4* rd = (const float4*)(T + l15 * 260 + c * 32 + quad * 8);
        float4 u0 = rd[0], u1 = rd[1];
        hv[0]=u0.x; hv[1]=u0.y; hv[2]=u0.z; hv[3]=u0.w;
        hv[4]=u1.x; hv[5]=u1.y; hv[6]=u1.z; hv[7]=u1.w;
        split_bf16(hv, h1h[c], h1l[c]);
    }

    float s[4] = {0.f, 0.f, 0.f, 0.f};
    #pragma unroll 1
    for (int g = 0; g < 16; ++g) {
        f32x4 acc = {0.f,0.f,0.f,0.f};
        #pragma unroll
        for (int c = 0; c < 8; ++c) {
            FragCast bh, bl2;
            bh.u  = r2h[(c * 16 + g) * 64 + lane];
            bl2.u = r2l[(c * 16 + g) * 64 + lane];
            acc = __builtin_amdgcn_mfma_f32_16x16x32_bf16(h1h[c], bh.v,  acc, 0, 0, 0);
            acc = __builtin_amdgcn_mfma_f32_16x16x32_bf16(h1h[c], bl2.v, acc, 0, 0, 0);
            acc = __builtin_amdgcn_mfma_f32_16x16x32_bf16(h1l[c], bh.v,  acc, 0, 0, 0);
        }
        float rb  = Rb2[g * 16 + l15];
        float r3v = R3[g * 16 + l15];
        #pragma unroll
        for (int rg = 0; rg < 4; ++rg)
            s[rg] += seluf(acc[rg] + rb) * r3v;
    }
    #pragma unroll
    for (int rg = 0; rg < 4; ++rg) {
        s[rg] += __shfl_xor(s[rg], 1);
        s[rg] += __shfl_xor(s[rg], 2);
        s[rg] += __shfl_xor(s[rg], 4);
        s[rg] += __shfl_xor(s[rg], 8);
    }
    if (l15 == 0) {
        float rb3 = Rb3[0];
        #pragma unroll
        for (int rg = 0; rg < 4; ++rg)
            out[p0 + quad * 4 + rg] = s[rg] + rb3;
    }
}

extern "C" void kernel_launch(void* const* d_in, const int* in_sizes, int n_in,
                              void* d_out, int out_size, void* d_ws, size_t ws_size,
                              hipStream_t stream)
{
    const int*   links = (const int*)d_in[0];
    const float* cap = (const float*)d_in[3];
    const float* pol = (const float*)d_in[4];
    const float* wts = (const float*)d_in[5];
    const float* bw  = (const float*)d_in[6];
    const float* tos = (const float*)d_in[7];
    const float* pk  = (const float*)d_in[8];
    const float* avg = (const float*)d_in[9];
    const float* Wp  = (const float*)d_in[10];
    const float* Up  = (const float*)d_in[11];
    const float* bp  = (const float*)d_in[12];
    const float* Wl  = (const float*)d_in[13];
    const float* Ul  = (const float*)d_in[14];
    const float* bl  = (const float*)d_in[15];
    const float* R1  = (const float*)d_in[16];
    const float* Rb1 = (const float*)d_in[17];
    const float* R2  = (const float*)d_in[18];
    const float* Rb2 = (const float*)d_in[19];
    const float* R3  = (const float*)d_in[20];
    const float* Rb3 = (const float*)d_in[21];

    char* w = (char*)d_ws;
    size_t off = 0;
    auto alloc = [&](size_t bytes) {
        char* p = w + off;
        off += (bytes + 255) & ~(size_t)255;
        return p;
    };
    float*          path_state = (float*)alloc((size_t)NP * DIM * 4);
    float*          link_state = (float*)alloc((size_t)NLINKS * DIM * 4);
    float*          m          = (float*)alloc((size_t)E_TOT * DIM * 4);
    unsigned short* ls_hi      = (unsigned short*)alloc((size_t)NLINKS * DIM * 2);
    unsigned short* ls_lo      = (unsigned short*)alloc((size_t)NLINKS * DIM * 2);
    unsigned short* wfr        = (unsigned short*)alloc(4 * 3072 * 2);
    unsigned short* lfr        = (unsigned short*)alloc(4 * 3072 * 2);
    unsigned short* rfr        = (unsigned short*)alloc((size_t)(8192 + 65536) * 2 * 2);
    int*            cnt        = (int*)alloc((size_t)NLINKS * 4);
    int*            row_start  = (int*)alloc((size_t)(NLINKS + 1) * 4);
    int*            cursor     = (int*)alloc((size_t)NLINKS * 4);
    int*            slot       = (int*)alloc((size_t)E_TOT * 4);

    init_kernel<<<(NP + 255) / 256, 256, 0, stream>>>(cap, pol, wts, bw, tos, pk, avg,
                                                      link_state, path_state, ls_hi, ls_lo);
    hipMemsetAsync(cnt, 0, (size_t)NLINKS * 4, stream);
    csr_count  <<<(E_TOT + 255) / 256, 256, 0, stream>>>(links, cnt);
    csr_scan   <<<1, 256, 0, stream>>>(cnt, row_start, cursor);
    csr_scatter<<<(E_TOT + 255) / 256, 256, 0, stream>>>(links, cursor, slot);
    wprep_kernel<<<12, 256, 0, stream>>>(Wp, Up, wfr);
    wprep_kernel<<<12, 256, 0, stream>>>(Wl, Ul, lfr);
    rprep_kernel<<<(8192 + 65536 + 255) / 256, 256, 0, stream>>>(R1, R2, rfr);

    const int PGRID = (NP / 16 + 3) / 4;
    const int LGRID = (NLINKS / 16 + 3) / 4;
    for (int it = 0; it < TITERS; ++it) {
        if (it < TITERS - 1) {
            path_kernel<true><<<PGRID, 256, 0, stream>>>(links, wfr, bp, ls_hi, ls_lo,
                                                         slot, path_state, m);
            aglk_kernel<<<LGRID, 256, 0, stream>>>(row_start, m, lfr, bl,
                                                   link_state, ls_hi, ls_lo);
        } else {
            path_kernel<false><<<PGRID, 256, 0, stream>>>(links, wfr, bp, ls_hi, ls_lo,
                                                          slot, path_state, m);
        }
    }
    readout_kernel<<<(NP / 16 + 1) / 2, 128, 0, stream>>>(path_state, rfr, Rb1, Rb2,
                                                          R3, Rb3, (float*)d_out);
}

// Round 15
// 819.300 us; speedup vs baseline: 1.3616x; 1.0326x over previous
//
#include <hip/hip_runtime.h>
#include <hip/hip_bf16.h>

#define NP     100000   // n_paths
#define PLEN   5        // path length
#define NLINKS 10000    // n_links
#define DIM    32       // state dim
#define TITERS 8        // message passing iterations
#define E_TOT  (NP * PLEN)

using bf16x8 = __attribute__((ext_vector_type(8))) short;
using f32x4  = __attribute__((ext_vector_type(4))) float;
union FragCast { uint4 u; bf16x8 v; };

// ---------- helpers ----------
__device__ __forceinline__ float fast_sigmoid(float v) {
    return 1.0f / (1.0f + __expf(-v));
}
__device__ __forceinline__ float fast_tanh(float v) {
    float e = __expf(-2.0f * fabsf(v));
    float t = (1.0f - e) / (1.0f + e);
    return v >= 0.0f ? t : -t;
}
__device__ __forceinline__ float seluf(float v) {
    const float sc = 1.0507009873554805f;
    const float al = 1.6732632423543772f;
    return v > 0.0f ? sc * v : sc * al * (__expf(v) - 1.0f);
}
__device__ __forceinline__ unsigned short f2bf(float f) {
    union { float f; unsigned u; } c; c.f = f;
    unsigned u = c.u;
    return (unsigned short)((u + 0x7fffu + ((u >> 16) & 1u)) >> 16);
}
__device__ __forceinline__ float bf2f(unsigned short b) {
    union { unsigned u; float f; } c; c.u = ((unsigned)b) << 16;
    return c.f;
}
__device__ __forceinline__ void split_bf16(const float (&v)[8], bf16x8& hi, bf16x8& lo) {
    unsigned uh[4], ul[4];
    #pragma unroll
    for (int i = 0; i < 4; ++i) {
        unsigned short h0 = f2bf(v[2*i]),   h1 = f2bf(v[2*i+1]);
        float r0 = v[2*i] - bf2f(h0),       r1 = v[2*i+1] - bf2f(h1);
        unsigned short l0 = f2bf(r0),       l1 = f2bf(r1);
        uh[i] = (unsigned)h0 | ((unsigned)h1 << 16);
        ul[i] = (unsigned)l0 | ((unsigned)l1 << 16);
    }
    FragCast ch, cl;
    ch.u.x = uh[0]; ch.u.y = uh[1]; ch.u.z = uh[2]; ch.u.w = uh[3];
    cl.u.x = ul[0]; cl.u.y = ul[1]; cl.u.z = ul[2]; cl.u.w = ul[3];
    hi = ch.v; lo = cl.v;
}

// ---------- init (also writes hi/lo split of initial link_state) ----------
__global__ __launch_bounds__(256) void init_kernel(
    const float* __restrict__ cap, const float* __restrict__ pol, const float* __restrict__ wts,
    const float* __restrict__ bw,  const float* __restrict__ tos,
    const float* __restrict__ pk,  const float* __restrict__ avg,
    float* __restrict__ link_state, float* __restrict__ path_state,
    unsigned short* __restrict__ ls_hi, unsigned short* __restrict__ ls_lo)
{
    int i = blockIdx.x * 256 + threadIdx.x;
    if (i < NLINKS) {
        float row[DIM];
        #pragma unroll
        for (int c = 0; c < DIM; ++c) row[c] = 0.0f;
        row[0] = cap[i]; row[1] = pol[i]; row[2] = wts[i];
        float4* o = (float4*)(link_state + (size_t)i * DIM);
        #pragma unroll
        for (int c = 0; c < 8; ++c) {
            float4 v = { row[4*c], row[4*c+1], row[4*c+2], row[4*c+3] };
            o[c] = v;
        }
        unsigned ush[16], usl[16];
        #pragma unroll
        for (int c = 0; c < 16; ++c) {
            unsigned short h0 = f2bf(row[2*c]), h1 = f2bf(row[2*c+1]);
            unsigned short l0 = f2bf(row[2*c] - bf2f(h0));
            unsigned short l1 = f2bf(row[2*c+1] - bf2f(h1));
            ush[c] = (unsigned)h0 | ((unsigned)h1 << 16);
            usl[c] = (unsigned)l0 | ((unsigned)l1 << 16);
        }
        uint4* oh = (uint4*)(ls_hi + (size_t)i * DIM);
        uint4* ol = (uint4*)(ls_lo + (size_t)i * DIM);
        #pragma unroll
        for (int q = 0; q < 4; ++q) {
            uint4 vh = { ush[4*q], ush[4*q+1], ush[4*q+2], ush[4*q+3] };
            uint4 vl = { usl[4*q], usl[4*q+1], usl[4*q+2], usl[4*q+3] };
            oh[q] = vh; ol[q] = vl;
        }
    }
    if (i < NP) {
        float row[DIM];
        #pragma unroll
        for (int c = 0; c < DIM; ++c) row[c] = 0.0f;
        row[0] = bw[i]; row[1] = tos[i]; row[2] = pk[i]; row[3] = avg[i];
        float4* o = (float4*)(path_state + (size_t)i * DIM);
        #pragma unroll
        for (int c = 0; c < 8; ++c) {
            float4 v = { row[4*c], row[4*c+1], row[4*c+2], row[4*c+3] };
            o[c] = v;
        }
    }
}

// ---------- CSR build ----------
__global__ __launch_bounds__(256) void csr_count(const int* __restrict__ links,
                                                 int* __restrict__ cnt)
{
    int e = blockIdx.x * 256 + threadIdx.x;
    if (e < E_TOT) atomicAdd(&cnt[links[e]], 1);
}

// single block; 2-pass chunked scan (8 barriers vs old 320)
__global__ __launch_bounds__(256) void csr_scan(const int* __restrict__ cnt,
                                                int* __restrict__ row_start,
                                                int* __restrict__ cursor)
{
    __shared__ int s[256];
    int t = threadIdx.x;
    const int CH = (NLINKS + 255) / 256;   // 40
    int base = t * CH;
    int sum = 0;
    for (int i = 0; i < CH; ++i) {
        int idx = base + i;
        if (idx < NLINKS) sum += cnt[idx];
    }
    s[t] = sum;
    __syncthreads();
    for (int off = 1; off < 256; off <<= 1) {
        int v = (t >= off) ? s[t - off] : 0;
        __syncthreads();
        s[t] += v;
        __syncthreads();
    }
    int run = s[t] - sum;                  // exclusive prefix of this chunk
    for (int i = 0; i < CH; ++i) {
        int idx = base + i;
        if (idx < NLINKS) {
            row_start[idx] = run;
            cursor[idx]    = run;
            run += cnt[idx];
        }
    }
    if (t == 255) row_start[NLINKS] = s[255];   // total == E_TOT
}

__global__ __launch_bounds__(256) void csr_scatter(const int* __restrict__ links,
                                                   int* __restrict__ cursor,
                                                   int* __restrict__ slot)
{
    int e = blockIdx.x * 256 + threadIdx.x;
    if (e < E_TOT) slot[e] = atomicAdd(&cursor[links[e]], 1);
}

// ---------- once per launch: GRU weights -> MFMA B-frags (hi/lo) ----------
__global__ __launch_bounds__(256) void wprep_kernel(const float* __restrict__ W,
                                                    const float* __restrict__ U,
                                                    unsigned short* __restrict__ ofr)
{
    int idx = blockIdx.x * 256 + threadIdx.x;
    if (idx >= 6 * 64 * 8) return;
    int j = idx & 7, lane = (idx >> 3) & 63, g = idx >> 9;
    int k = (lane >> 4) * 8 + j;
    int n = g * 16 + (lane & 15);
    float w = W[k * 96 + n];
    float u = U[k * 96 + n];
    unsigned short whi = f2bf(w); unsigned short wlo = f2bf(w - bf2f(whi));
    unsigned short uhi = f2bf(u); unsigned short ulo = f2bf(u - bf2f(uhi));
    ofr[0 * 3072 + idx] = whi;
    ofr[1 * 3072 + idx] = wlo;
    ofr[2 * 3072 + idx] = uhi;
    ofr[3 * 3072 + idx] = ulo;
}

// ---------- once per launch: readout R1/R2 -> MFMA B-frags (hi/lo) ----------
__global__ __launch_bounds__(256) void rprep_kernel(const float* __restrict__ R1,
                                                    const float* __restrict__ R2,
                                                    unsigned short* __restrict__ rfr)
{
    int idx = blockIdx.x * 256 + threadIdx.x;
    if (idx >= 8192 + 65536) return;
    if (idx < 8192) {
        int j = idx & 7, lane = (idx >> 3) & 63, g = idx >> 9;
        int k = (lane >> 4) * 8 + j;
        int n = g * 16 + (lane & 15);
        float v = R1[k * 256 + n];
        unsigned short hi = f2bf(v);
        rfr[idx] = hi;
        rfr[8192 + idx] = f2bf(v - bf2f(hi));
    } else {
        int idx2 = idx - 8192;
        int j = idx2 & 7, lane = (idx2 >> 3) & 63, tile = idx2 >> 9;
        int c = tile >> 4, g = tile & 15;
        int k = c * 32 + (lane >> 4) * 8 + j;
        int n = g * 16 + (lane & 15);
        float v = R2[k * 256 + n];
        unsigned short hi = f2bf(v);
        rfr[16384 + idx2] = hi;
        rfr[16384 + 65536 + idx2] = f2bf(v - bf2f(hi));
    }
}

// ---------- shared device body: 5-hop MFMA path GRU for one 16-path tile ----
// T = wave-private LDS (>= 16*36 floats). Result: hA = final h (A-row layout).
template <bool STORE_M>
__device__ __forceinline__ void path_gru_body(
    int p, int l15, int quad, float* T,
    const int* __restrict__ links,
    const unsigned short* __restrict__ wfr,
    const float* __restrict__ bp,
    const unsigned short* __restrict__ ls_hi,
    const unsigned short* __restrict__ ls_lo,
    const int* __restrict__ slot,
    const float* __restrict__ path_state,
    float* __restrict__ m,
    float (&hA)[8])
{
    int lane = quad * 16 + l15;
    int lk[PLEN];
    #pragma unroll
    for (int l = 0; l < PLEN; ++l) lk[l] = links[p * PLEN + l];
    bf16x8 pxh[PLEN], pxl[PLEN];
    #pragma unroll
    for (int l = 0; l < PLEN; ++l) {
        FragCast ch, cl;
        ch.u = *(const uint4*)(ls_hi + (size_t)lk[l] * DIM + quad * 8);
        cl.u = *(const uint4*)(ls_lo + (size_t)lk[l] * DIM + quad * 8);
        pxh[l] = ch.v; pxl[l] = cl.v;
    }
    int sl[PLEN];
    if (STORE_M) {
        #pragma unroll
        for (int l = 0; l < PLEN; ++l) sl[l] = slot[p * PLEN + l];
    }

    bf16x8 Wh[6], Wl[6], Uh[6], Ul[6];
    {
        const uint4* base = (const uint4*)wfr;
        #pragma unroll
        for (int g = 0; g < 6; ++g) {
            FragCast a;
            a.u = base[0 * 384 + g * 64 + lane]; Wh[g] = a.v;
            a.u = base[1 * 384 + g * 64 + lane]; Wl[g] = a.v;
            a.u = base[2 * 384 + g * 64 + lane]; Uh[g] = a.v;
            a.u = base[3 * 384 + g * 64 + lane]; Ul[g] = a.v;
        }
    }
    float bz[2], br[2], bnx[2], bnh[2];
    #pragma unroll
    for (int hf = 0; hf < 2; ++hf) {
        int c = hf * 16 + l15;
        bz[hf]  = bp[c]      + bp[96 + c];
        br[hf]  = bp[32 + c] + bp[96 + 32 + c];
        bnx[hf] = bp[64 + c];
        bnh[hf] = bp[96 + 64 + c];
    }

    {
        const float4* src = (const float4*)(path_state + (size_t)p * DIM + quad * 8);
        float4 v0 = src[0], v1 = src[1];
        hA[0]=v0.x; hA[1]=v0.y; hA[2]=v0.z; hA[3]=v0.w;
        hA[4]=v1.x; hA[5]=v1.y; hA[6]=v1.z; hA[7]=v1.w;
    }
    #pragma unroll
    for (int j = 0; j < 8; ++j) T[l15 * 36 + quad * 8 + j] = hA[j];
    __asm__ volatile("s_waitcnt lgkmcnt(0)" ::: "memory");
    float hC[2][4];
    #pragma unroll
    for (int hf = 0; hf < 2; ++hf)
        #pragma unroll
        for (int rg = 0; rg < 4; ++rg)
            hC[hf][rg] = T[(quad * 4 + rg) * 36 + hf * 16 + l15];

    bf16x8 ah, al;
    split_bf16(hA, ah, al);

    #pragma unroll
    for (int l = 0; l < PLEN; ++l) {
        bf16x8 xh = pxh[l], xl = pxl[l];
        #pragma unroll
        for (int hf = 0; hf < 2; ++hf) {
            f32x4 az = {0.f,0.f,0.f,0.f}, ar = {0.f,0.f,0.f,0.f};
            f32x4 axn = {0.f,0.f,0.f,0.f}, ahg = {0.f,0.f,0.f,0.f};
            int gz = hf, gr = 2 + hf, gn = 4 + hf;
            az = __builtin_amdgcn_mfma_f32_16x16x32_bf16(xh, Wh[gz], az, 0, 0, 0);
            az = __builtin_amdgcn_mfma_f32_16x16x32_bf16(xh, Wl[gz], az, 0, 0, 0);
            az = __builtin_amdgcn_mfma_f32_16x16x32_bf16(xl, Wh[gz], az, 0, 0, 0);
            az = __builtin_amdgcn_mfma_f32_16x16x32_bf16(ah, Uh[gz], az, 0, 0, 0);
            az = __builtin_amdgcn_mfma_f32_16x16x32_bf16(ah, Ul[gz], az, 0, 0, 0);
            az = __builtin_amdgcn_mfma_f32_16x16x32_bf16(al, Uh[gz], az, 0, 0, 0);
            ar = __builtin_amdgcn_mfma_f32_16x16x32_bf16(xh, Wh[gr], ar, 0, 0, 0);
            ar = __builtin_amdgcn_mfma_f32_16x16x32_bf16(xh, Wl[gr], ar, 0, 0, 0);
            ar = __builtin_amdgcn_mfma_f32_16x16x32_bf16(xl, Wh[gr], ar, 0, 0, 0);
            ar = __builtin_amdgcn_mfma_f32_16x16x32_bf16(ah, Uh[gr], ar, 0, 0, 0);
            ar = __builtin_amdgcn_mfma_f32_16x16x32_bf16(ah, Ul[gr], ar, 0, 0, 0);
            ar = __builtin_amdgcn_mfma_f32_16x16x32_bf16(al, Uh[gr], ar, 0, 0, 0);
            axn = __builtin_amdgcn_mfma_f32_16x16x32_bf16(xh, Wh[gn], axn, 0, 0, 0);
            axn = __builtin_amdgcn_mfma_f32_16x16x32_bf16(xh, Wl[gn], axn, 0, 0, 0);
            axn = __builtin_amdgcn_mfma_f32_16x16x32_bf16(xl, Wh[gn], axn, 0, 0, 0);
            ahg = __builtin_amdgcn_mfma_f32_16x16x32_bf16(ah, Uh[gn], ahg, 0, 0, 0);
            ahg = __builtin_amdgcn_mfma_f32_16x16x32_bf16(ah, Ul[gn], ahg, 0, 0, 0);
            ahg = __builtin_amdgcn_mfma_f32_16x16x32_bf16(al, Uh[gn], ahg, 0, 0, 0);
            #pragma unroll
            for (int rg = 0; rg < 4; ++rg) {
                float z  = fast_sigmoid(az[rg] + bz[hf]);
                float r  = fast_sigmoid(ar[rg] + br[hf]);
                float hn = fast_tanh(axn[rg] + bnx[hf] + r * (ahg[rg] + bnh[hf]));
                hC[hf][rg] = z * hC[hf][rg] + (1.0f - z) * hn;
            }
        }

        __asm__ volatile("s_waitcnt lgkmcnt(0)" ::: "memory");
        #pragma unroll
        for (int hf = 0; hf < 2; ++hf)
            #pragma unroll
            for (int rg = 0; rg < 4; ++rg)
                T[(quad * 4 + rg) * 36 + hf * 16 + l15] = hC[hf][rg];
        __asm__ volatile("s_waitcnt lgkmcnt(0)" ::: "memory");
        {
            const float4* rd = (const float4*)(T + l15 * 36 + quad * 8);
            float4 v0 = rd[0], v1 = rd[1];
            hA[0]=v0.x; hA[1]=v0.y; hA[2]=v0.z; hA[3]=v0.w;
            hA[4]=v1.x; hA[5]=v1.y; hA[6]=v1.z; hA[7]=v1.w;
        }
        if (STORE_M) {
            float4* dst = (float4*)(m + (size_t)sl[l] * DIM + quad * 8);
            float4 v0 = { hA[0], hA[1], hA[2], hA[3] };
            float4 v1 = { hA[4], hA[5], hA[6], hA[7] };
            dst[0] = v0; dst[1] = v1;
        }
        if (l < PLEN - 1) split_bf16(hA, ah, al);
    }
}

// ---------- MFMA path GRU kernel (iterations 0..6, stores m + path_state) ----
__global__ __launch_bounds__(256) void path_kernel(
    const int*   __restrict__ links,
    const unsigned short* __restrict__ wfr,
    const float* __restrict__ bp,
    const unsigned short* __restrict__ ls_hi,
    const unsigned short* __restrict__ ls_lo,
    const int*   __restrict__ slot,
    float* __restrict__ path_state,
    float* __restrict__ m)
{
    __shared__ __align__(16) float T4[4][16 * 36];
    int t = threadIdx.x;
    int wave = t >> 6, lane = t & 63;
    int l15 = lane & 15, quad = lane >> 4;
    int p0 = (blockIdx.x * 4 + wave) * 16;
    if (p0 >= NP) return;
    int p = p0 + l15;
    float hA[8];
    path_gru_body<true>(p, l15, quad, T4[wave], links, wfr, bp, ls_hi, ls_lo,
                        slot, path_state, m, hA);
    float4* ho = (float4*)(path_state + (size_t)p * DIM + quad * 8);
    float4 v0 = { hA[0], hA[1], hA[2], hA[3] };
    float4 v1 = { hA[4], hA[5], hA[6], hA[7] };
    ho[0] = v0; ho[1] = v1;
}

// ---------- fused aggregate + MFMA link GRU (R13-verified, unchanged) ----------
__global__ __launch_bounds__(256) void aglk_kernel(
    const int* __restrict__ row_start,
    const float* __restrict__ m,
    const unsigned short* __restrict__ lfr,
    const float* __restrict__ bl,
    float* __restrict__ link_state,
    unsigned short* __restrict__ ls_hi, unsigned short* __restrict__ ls_lo)
{
    __shared__ __align__(16) float T4[4][16 * 36];
    int t = threadIdx.x;
    int wave = t >> 6, lane = t & 63;
    int l15 = lane & 15, quad = lane >> 4;
    int lb = (blockIdx.x * 4 + wave) * 16;
    if (lb >= NLINKS) return;
    float* T = T4[wave];
    int link = lb + l15;

    bf16x8 Wh[6], Wlo[6], Uh[6], Ulo[6];
    {
        const uint4* base = (const uint4*)lfr;
        #pragma unroll
        for (int g = 0; g < 6; ++g) {
            FragCast a;
            a.u = base[0 * 384 + g * 64 + lane]; Wh[g]  = a.v;
            a.u = base[1 * 384 + g * 64 + lane]; Wlo[g] = a.v;
            a.u = base[2 * 384 + g * 64 + lane]; Uh[g]  = a.v;
            a.u = base[3 * 384 + g * 64 + lane]; Ulo[g] = a.v;
        }
    }
    float bz[2], br[2], bnx[2], bnh[2];
    #pragma unroll
    for (int hf = 0; hf < 2; ++hf) {
        int c = hf * 16 + l15;
        bz[hf]  = bl[c]      + bl[96 + c];
        br[hf]  = bl[32 + c] + bl[96 + 32 + c];
        bnx[hf] = bl[64 + c];
        bnh[hf] = bl[96 + 64 + c];
    }

    int s0 = row_start[link], s1 = row_start[link + 1];
    float x8[8] = {0.f,0.f,0.f,0.f,0.f,0.f,0.f,0.f};
    int i = s0;
    for (; i + 4 <= s1; i += 4) {
        #pragma unroll
        for (int u = 0; u < 4; ++u) {
            const float4* mr = (const float4*)(m + (size_t)(i + u) * DIM + quad * 8);
            float4 a = mr[0], b = mr[1];
            x8[0] += a.x; x8[1] += a.y; x8[2] += a.z; x8[3] += a.w;
            x8[4] += b.x; x8[5] += b.y; x8[6] += b.z; x8[7] += b.w;
        }
    }
    for (; i < s1; ++i) {
        const float4* mr = (const float4*)(m + (size_t)i * DIM + quad * 8);
        float4 a = mr[0], b = mr[1];
        x8[0] += a.x; x8[1] += a.y; x8[2] += a.z; x8[3] += a.w;
        x8[4] += b.x; x8[5] += b.y; x8[6] += b.z; x8[7] += b.w;
    }
    bf16x8 xh, xl;
    split_bf16(x8, xh, xl);

    float hA[8];
    {
        const float4* src = (const float4*)(link_state + (size_t)link * DIM + quad * 8);
        float4 v0 = src[0], v1 = src[1];
        hA[0]=v0.x; hA[1]=v0.y; hA[2]=v0.z; hA[3]=v0.w;
        hA[4]=v1.x; hA[5]=v1.y; hA[6]=v1.z; hA[7]=v1.w;
    }
    #pragma unroll
    for (int j = 0; j < 8; ++j) T[l15 * 36 + quad * 8 + j] = hA[j];
    __asm__ volatile("s_waitcnt lgkmcnt(0)" ::: "memory");
    float hC[2][4];
    #pragma unroll
    for (int hf = 0; hf < 2; ++hf)
        #pragma unroll
        for (int rg = 0; rg < 4; ++rg)
            hC[hf][rg] = T[(quad * 4 + rg) * 36 + hf * 16 + l15];
    bf16x8 ah, al;
    split_bf16(hA, ah, al);

    #pragma unroll
    for (int hf = 0; hf < 2; ++hf) {
        f32x4 az = {0.f,0.f,0.f,0.f}, ar = {0.f,0.f,0.f,0.f};
        f32x4 axn = {0.f,0.f,0.f,0.f}, ahg = {0.f,0.f,0.f,0.f};
        int gz = hf, gr = 2 + hf, gn = 4 + hf;
        az = __builtin_amdgcn_mfma_f32_16x16x32_bf16(xh, Wh[gz],  az, 0, 0, 0);
        az = __builtin_amdgcn_mfma_f32_16x16x32_bf16(xh, Wlo[gz], az, 0, 0, 0);
        az = __builtin_amdgcn_mfma_f32_16x16x32_bf16(xl, Wh[gz],  az, 0, 0, 0);
        az = __builtin_amdgcn_mfma_f32_16x16x32_bf16(ah, Uh[gz],  az, 0, 0, 0);
        az = __builtin_amdgcn_mfma_f32_16x16x32_bf16(ah, Ulo[gz], az, 0, 0, 0);
        az = __builtin_amdgcn_mfma_f32_16x16x32_bf16(al, Uh[gz],  az, 0, 0, 0);
        ar = __builtin_amdgcn_mfma_f32_16x16x32_bf16(xh, Wh[gr],  ar, 0, 0, 0);
        ar = __builtin_amdgcn_mfma_f32_16x16x32_bf16(xh, Wlo[gr], ar, 0, 0, 0);
        ar = __builtin_amdgcn_mfma_f32_16x16x32_bf16(xl, Wh[gr],  ar, 0, 0, 0);
        ar = __builtin_amdgcn_mfma_f32_16x16x32_bf16(ah, Uh[gr],  ar, 0, 0, 0);
        ar = __builtin_amdgcn_mfma_f32_16x16x32_bf16(ah, Ulo[gr], ar, 0, 0, 0);
        ar = __builtin_amdgcn_mfma_f32_16x16x32_bf16(al, Uh[gr],  ar, 0, 0, 0);
        axn = __builtin_amdgcn_mfma_f32_16x16x32_bf16(xh, Wh[gn],  axn, 0, 0, 0);
        axn = __builtin_amdgcn_mfma_f32_16x16x32_bf16(xh, Wlo[gn], axn, 0, 0, 0);
        axn = __builtin_amdgcn_mfma_f32_16x16x32_bf16(xl, Wh[gn],  axn, 0, 0, 0);
        ahg = __builtin_amdgcn_mfma_f32_16x16x32_bf16(ah, Uh[gn],  ahg, 0, 0, 0);
        ahg = __builtin_amdgcn_mfma_f32_16x16x32_bf16(ah, Ulo[gn], ahg, 0, 0, 0);
        ahg = __builtin_amdgcn_mfma_f32_16x16x32_bf16(al, Uh[gn],  ahg, 0, 0, 0);
        #pragma unroll
        for (int rg = 0; rg < 4; ++rg) {
            float z  = fast_sigmoid(az[rg] + bz[hf]);
            float r  = fast_sigmoid(ar[rg] + br[hf]);
            float hn = fast_tanh(axn[rg] + bnx[hf] + r * (ahg[rg] + bnh[hf]));
            hC[hf][rg] = z * hC[hf][rg] + (1.0f - z) * hn;
        }
    }

    __asm__ volatile("s_waitcnt lgkmcnt(0)" ::: "memory");
    #pragma unroll
    for (int hf = 0; hf < 2; ++hf)
        #pragma unroll
        for (int rg = 0; rg < 4; ++rg)
            T[(quad * 4 + rg) * 36 + hf * 16 + l15] = hC[hf][rg];
    __asm__ volatile("s_waitcnt lgkmcnt(0)" ::: "memory");
    {
        const float4* rd = (const float4*)(T + l15 * 36 + quad * 8);
        float4 v0 = rd[0], v1 = rd[1];
        hA[0]=v0.x; hA[1]=v0.y; hA[2]=v0.z; hA[3]=v0.w;
        hA[4]=v1.x; hA[5]=v1.y; hA[6]=v1.z; hA[7]=v1.w;
    }
    float4* ho = (float4*)(link_state + (size_t)link * DIM + quad * 8);
    float4 v0 = { hA[0], hA[1], hA[2], hA[3] };
    float4 v1 = { hA[4], hA[5], hA[6], hA[7] };
    ho[0] = v0; ho[1] = v1;
    bf16x8 nh, nl;
    split_bf16(hA, nh, nl);
    FragCast ch, cl;
    ch.v = nh; cl.v = nl;
    *(uint4*)(ls_hi + (size_t)link * DIM + quad * 8) = ch.u;
    *(uint4*)(ls_lo + (size_t)link * DIM + quad * 8) = cl.u;
}

// ---------- fused: final path GRU iteration + MFMA readout ----------
// wave = 16 paths; phase 1 = 5-hop GRU (weights die after), phase 2 = MLP.
__global__ __launch_bounds__(128, 1) void readout_kernel(
    const int*   __restrict__ links,
    const unsigned short* __restrict__ wfr,
    const float* __restrict__ bp,
    const unsigned short* __restrict__ ls_hi,
    const unsigned short* __restrict__ ls_lo,
    const float* __restrict__ path_state,
    const unsigned short* __restrict__ rfr,
    const float* __restrict__ Rb1, const float* __restrict__ Rb2,
    const float* __restrict__ R3,  const float* __restrict__ Rb3,
    float* __restrict__ out)
{
    __shared__ __align__(16) float T2[2][16 * 260];   // 33.3 KB (GRU uses first 576 floats)
    int t = threadIdx.x;
    int wave = t >> 6, lane = t & 63;
    int l15 = lane & 15, quad = lane >> 4;
    int p0 = (blockIdx.x * 2 + wave) * 16;
    if (p0 >= NP) return;
    float* T = T2[wave];
    int p = p0 + l15;

    // ---- phase 1: final path GRU (no m store, no path_state writeback) ----
    float h0[8];
    path_gru_body<false>(p, l15, quad, T, links, wfr, bp, ls_hi, ls_lo,
                         nullptr, path_state, nullptr, h0);

    // ---- phase 2: readout MLP (R12-proven single-tile structure) ----
    const uint4* r1h = (const uint4*)rfr;
    const uint4* r1l = r1h + 1024;
    const uint4* r2h = r1l + 1024;
    const uint4* r2l = r2h + 8192;

    bf16x8 a0h, a0l;
    split_bf16(h0, a0h, a0l);
    #pragma unroll 1
    for (int g = 0; g < 16; ++g) {
        FragCast bh, bl2;
        bh.u  = r1h[g * 64 + lane];
        bl2.u = r1l[g * 64 + lane];
        f32x4 c = {0.f,0.f,0.f,0.f};
        c = __builtin_amdgcn_mfma_f32_16x16x32_bf16(a0h, bh.v,  c, 0, 0, 0);
        c = __builtin_amdgcn_mfma_f32_16x16x32_bf16(a0h, bl2.v, c, 0, 0, 0);
        c = __builtin_amdgcn_mfma_f32_16x16x32_bf16(a0l, bh.v,  c, 0, 0, 0);
        float rb = Rb1[g * 16 + l15];
        #pragma unroll
        for (int rg = 0; rg < 4; ++rg)
            T[(quad * 4 + rg) * 260 + g * 16 + l15] = seluf(c[rg] + rb);
    }
    __asm__ volatile("s_waitcnt lgkmcnt(0)" ::: "memory");

    bf16x8 h1h[8], h1l[8];
    #pragma unroll
    for (int c = 0; c < 8; ++c) {
        float hv[8];
        const float4* rd = (const float4*)(T + l15 * 260 + c * 32 + quad * 8);
        float4 u0 = rd[0], u1 = rd[1];
        hv[0]=u0.x; hv[1]=u0.y; hv[2]=u0.z; hv[3]=u0.w;
        hv[4]=u1.x; hv[5]=u1.y; hv[6]=u1.z; hv[7]=u1.w;
        split_bf16(hv, h1h[c], h1l[c]);
    }

    float s[4] = {0.f, 0.f, 0.f, 0.f};
    #pragma unroll 1
    for (int g = 0; g < 16; ++g) {
        f32x4 acc = {0.f,0.f,0.f,0.f};
        #pragma unroll
        for (int c = 0; c < 8; ++c) {
            FragCast bh, bl2;
            bh.u  = r2h[(c * 16 + g) * 64 + lane];
            bl2.u = r2l[(c * 16 + g) * 64 + lane];
            acc = __builtin_amdgcn_mfma_f32_16x16x32_bf16(h1h[c], bh.v,  acc, 0, 0, 0);
            acc = __builtin_amdgcn_mfma_f32_16x16x32_bf16(h1h[c], bl2.v, acc, 0, 0, 0);
            acc = __builtin_amdgcn_mfma_f32_16x16x32_bf16(h1l[c], bh.v,  acc, 0, 0, 0);
        }
        float rb  = Rb2[g * 16 + l15];
        float r3v = R3[g * 16 + l15];
        #pragma unroll
        for (int rg = 0; rg < 4; ++rg)
            s[rg] += seluf(acc[rg] + rb) * r3v;
    }
    #pragma unroll
    for (int rg = 0; rg < 4; ++rg) {
        s[rg] += __shfl_xor(s[rg], 1);
        s[rg] += __shfl_xor(s[rg], 2);
        s[rg] += __shfl_xor(s[rg], 4);
        s[rg] += __shfl_xor(s[rg], 8);
    }
    if (l15 == 0) {
        float rb3 = Rb3[0];
        #pragma unroll
        for (int rg = 0; rg < 4; ++rg)
            out[p0 + quad * 4 + rg] = s[rg] + rb3;
    }
}

extern "C" void kernel_launch(void* const* d_in, const int* in_sizes, int n_in,
                              void* d_out, int out_size, void* d_ws, size_t ws_size,
                              hipStream_t stream)
{
    const int*   links = (const int*)d_in[0];
    const float* cap = (const float*)d_in[3];
    const float* pol = (const float*)d_in[4];
    const float* wts = (const float*)d_in[5];
    const float* bw  = (const float*)d_in[6];
    const float* tos = (const float*)d_in[7];
    const float* pk  = (const float*)d_in[8];
    const float* avg = (const float*)d_in[9];
    const float* Wp  = (const float*)d_in[10];
    const float* Up  = (const float*)d_in[11];
    const float* bp  = (const float*)d_in[12];
    const float* Wl  = (const float*)d_in[13];
    const float* Ul  = (const float*)d_in[14];
    const float* bl  = (const float*)d_in[15];
    const float* R1  = (const float*)d_in[16];
    const float* Rb1 = (const float*)d_in[17];
    const float* R2  = (const float*)d_in[18];
    const float* Rb2 = (const float*)d_in[19];
    const float* R3  = (const float*)d_in[20];
    const float* Rb3 = (const float*)d_in[21];

    char* w = (char*)d_ws;
    size_t off = 0;
    auto alloc = [&](size_t bytes) {
        char* p = w + off;
        off += (bytes + 255) & ~(size_t)255;
        return p;
    };
    float*          path_state = (float*)alloc((size_t)NP * DIM * 4);
    float*          link_state = (float*)alloc((size_t)NLINKS * DIM * 4);
    float*          m          = (float*)alloc((size_t)E_TOT * DIM * 4);
    unsigned short* ls_hi      = (unsigned short*)alloc((size_t)NLINKS * DIM * 2);
    unsigned short* ls_lo      = (unsigned short*)alloc((size_t)NLINKS * DIM * 2);
    unsigned short* wfr        = (unsigned short*)alloc(4 * 3072 * 2);
    unsigned short* lfr        = (unsigned short*)alloc(4 * 3072 * 2);
    unsigned short* rfr        = (unsigned short*)alloc((size_t)(8192 + 65536) * 2 * 2);
    int*            cnt        = (int*)alloc((size_t)NLINKS * 4);
    int*            row_start  = (int*)alloc((size_t)(NLINKS + 1) * 4);
    int*            cursor     = (int*)alloc((size_t)NLINKS * 4);
    int*            slot       = (int*)alloc((size_t)E_TOT * 4);

    init_kernel<<<(NP + 255) / 256, 256, 0, stream>>>(cap, pol, wts, bw, tos, pk, avg,
                                                      link_state, path_state, ls_hi, ls_lo);
    hipMemsetAsync(cnt, 0, (size_t)NLINKS * 4, stream);
    csr_count  <<<(E_TOT + 255) / 256, 256, 0, stream>>>(links, cnt);
    csr_scan   <<<1, 256, 0, stream>>>(cnt, row_start, cursor);
    csr_scatter<<<(E_TOT + 255) / 256, 256, 0, stream>>>(links, cursor, slot);
    wprep_kernel<<<12, 256, 0, stream>>>(Wp, Up, wfr);
    wprep_kernel<<<12, 256, 0, stream>>>(Wl, Ul, lfr);
    rprep_kernel<<<(8192 + 65536 + 255) / 256, 256, 0, stream>>>(R1, R2, rfr);

    const int PGRID = (NP / 16 + 3) / 4;
    const int LGRID = (NLINKS / 16 + 3) / 4;
    for (int it = 0; it < TITERS - 1; ++it) {
        path_kernel<<<PGRID, 256, 0, stream>>>(links, wfr, bp, ls_hi, ls_lo,
                                               slot, path_state, m);
        aglk_kernel<<<LGRID, 256, 0, stream>>>(row_start, m, lfr, bl,
                                               link_state, ls_hi, ls_lo);
    }
    // final path iteration fused into readout
    readout_kernel<<<(NP / 16 + 1) / 2, 128, 0, stream>>>(links, wfr, bp, ls_hi, ls_lo,
                                                          path_state, rfr, Rb1, Rb2,
                                                          R3, Rb3, (float*)d_out);
}

// Round 18
// 818.616 us; speedup vs baseline: 1.3628x; 1.0008x over previous
//
#include <hip/hip_runtime.h>
#include <hip/hip_bf16.h>

#define NP     100000   // n_paths
#define PLEN   5        // path length
#define NLINKS 10000    // n_links
#define DIM    32       // state dim
#define TITERS 8        // message passing iterations
#define E_TOT  (NP * PLEN)

using bf16x8 = __attribute__((ext_vector_type(8))) short;
using f32x4  = __attribute__((ext_vector_type(4))) float;
union FragCast { uint4 u; bf16x8 v; };

// ---------- helpers ----------
__device__ __forceinline__ float fast_sigmoid(float v) {
    return 1.0f / (1.0f + __expf(-v));
}
__device__ __forceinline__ float fast_tanh(float v) {
    float e = __expf(-2.0f * fabsf(v));
    float t = (1.0f - e) / (1.0f + e);
    return v >= 0.0f ? t : -t;
}
__device__ __forceinline__ float seluf(float v) {
    const float sc = 1.0507009873554805f;
    const float al = 1.6732632423543772f;
    return v > 0.0f ? sc * v : sc * al * (__expf(v) - 1.0f);
}
__device__ __forceinline__ unsigned short f2bf(float f) {
    union { float f; unsigned u; } c; c.f = f;
    unsigned u = c.u;
    return (unsigned short)((u + 0x7fffu + ((u >> 16) & 1u)) >> 16);
}
__device__ __forceinline__ float bf2f(unsigned short b) {
    union { unsigned u; float f; } c; c.u = ((unsigned)b) << 16;
    return c.f;
}
__device__ __forceinline__ void split_bf16(const float (&v)[8], bf16x8& hi, bf16x8& lo) {
    unsigned uh[4], ul[4];
    #pragma unroll
    for (int i = 0; i < 4; ++i) {
        unsigned short h0 = f2bf(v[2*i]),   h1 = f2bf(v[2*i+1]);
        float r0 = v[2*i] - bf2f(h0),       r1 = v[2*i+1] - bf2f(h1);
        unsigned short l0 = f2bf(r0),       l1 = f2bf(r1);
        uh[i] = (unsigned)h0 | ((unsigned)h1 << 16);
        ul[i] = (unsigned)l0 | ((unsigned)l1 << 16);
    }
    FragCast ch, cl;
    ch.u.x = uh[0]; ch.u.y = uh[1]; ch.u.z = uh[2]; ch.u.w = uh[3];
    cl.u.x = ul[0]; cl.u.y = ul[1]; cl.u.z = ul[2]; cl.u.w = ul[3];
    hi = ch.v; lo = cl.v;
}

// ---------- init (also writes hi/lo split of initial link_state) ----------
__global__ __launch_bounds__(256) void init_kernel(
    const float* __restrict__ cap, const float* __restrict__ pol, const float* __restrict__ wts,
    const float* __restrict__ bw,  const float* __restrict__ tos,
    const float* __restrict__ pk,  const float* __restrict__ avg,
    float* __restrict__ link_state, float* __restrict__ path_state,
    unsigned short* __restrict__ ls_hi, unsigned short* __restrict__ ls_lo)
{
    int i = blockIdx.x * 256 + threadIdx.x;
    if (i < NLINKS) {
        float row[DIM];
        #pragma unroll
        for (int c = 0; c < DIM; ++c) row[c] = 0.0f;
        row[0] = cap[i]; row[1] = pol[i]; row[2] = wts[i];
        float4* o = (float4*)(link_state + (size_t)i * DIM);
        #pragma unroll
        for (int c = 0; c < 8; ++c) {
            float4 v = { row[4*c], row[4*c+1], row[4*c+2], row[4*c+3] };
            o[c] = v;
        }
        unsigned ush[16], usl[16];
        #pragma unroll
        for (int c = 0; c < 16; ++c) {
            unsigned short h0 = f2bf(row[2*c]), h1 = f2bf(row[2*c+1]);
            unsigned short l0 = f2bf(row[2*c] - bf2f(h0));
            unsigned short l1 = f2bf(row[2*c+1] - bf2f(h1));
            ush[c] = (unsigned)h0 | ((unsigned)h1 << 16);
            usl[c] = (unsigned)l0 | ((unsigned)l1 << 16);
        }
        uint4* oh = (uint4*)(ls_hi + (size_t)i * DIM);
        uint4* ol = (uint4*)(ls_lo + (size_t)i * DIM);
        #pragma unroll
        for (int q = 0; q < 4; ++q) {
            uint4 vh = { ush[4*q], ush[4*q+1], ush[4*q+2], ush[4*q+3] };
            uint4 vl = { usl[4*q], usl[4*q+1], usl[4*q+2], usl[4*q+3] };
            oh[q] = vh; ol[q] = vl;
        }
    }
    if (i < NP) {
        float row[DIM];
        #pragma unroll
        for (int c = 0; c < DIM; ++c) row[c] = 0.0f;
        row[0] = bw[i]; row[1] = tos[i]; row[2] = pk[i]; row[3] = avg[i];
        float4* o = (float4*)(path_state + (size_t)i * DIM);
        #pragma unroll
        for (int c = 0; c < 8; ++c) {
            float4 v = { row[4*c], row[4*c+1], row[4*c+2], row[4*c+3] };
            o[c] = v;
        }
    }
}

// ---------- CSR build ----------
__global__ __launch_bounds__(256) void csr_count(const int* __restrict__ links,
                                                 int* __restrict__ cnt)
{
    int e = blockIdx.x * 256 + threadIdx.x;
    if (e < E_TOT) atomicAdd(&cnt[links[e]], 1);
}

// single block; 2-pass chunked scan (8 barriers vs old 320)
__global__ __launch_bounds__(256) void csr_scan(const int* __restrict__ cnt,
                                                int* __restrict__ row_start,
                                                int* __restrict__ cursor)
{
    __shared__ int s[256];
    int t = threadIdx.x;
    const int CH = (NLINKS + 255) / 256;   // 40
    int base = t * CH;
    int sum = 0;
    for (int i = 0; i < CH; ++i) {
        int idx = base + i;
        if (idx < NLINKS) sum += cnt[idx];
    }
    s[t] = sum;
    __syncthreads();
    for (int off = 1; off < 256; off <<= 1) {
        int v = (t >= off) ? s[t - off] : 0;
        __syncthreads();
        s[t] += v;
        __syncthreads();
    }
    int run = s[t] - sum;                  // exclusive prefix of this chunk
    for (int i = 0; i < CH; ++i) {
        int idx = base + i;
        if (idx < NLINKS) {
            row_start[idx] = run;
            cursor[idx]    = run;
            run += cnt[idx];
        }
    }
    if (t == 255) row_start[NLINKS] = s[255];   // total == E_TOT
}

__global__ __launch_bounds__(256) void csr_scatter(const int* __restrict__ links,
                                                   int* __restrict__ cursor,
                                                   int* __restrict__ slot)
{
    int e = blockIdx.x * 256 + threadIdx.x;
    if (e < E_TOT) slot[e] = atomicAdd(&cursor[links[e]], 1);
}

// ---------- once per launch: GRU weights -> MFMA B-frags (hi/lo) ----------
__global__ __launch_bounds__(256) void wprep_kernel(const float* __restrict__ W,
                                                    const float* __restrict__ U,
                                                    unsigned short* __restrict__ ofr)
{
    int idx = blockIdx.x * 256 + threadIdx.x;
    if (idx >= 6 * 64 * 8) return;
    int j = idx & 7, lane = (idx >> 3) & 63, g = idx >> 9;
    int k = (lane >> 4) * 8 + j;
    int n = g * 16 + (lane & 15);
    float w = W[k * 96 + n];
    float u = U[k * 96 + n];
    unsigned short whi = f2bf(w); unsigned short wlo = f2bf(w - bf2f(whi));
    unsigned short uhi = f2bf(u); unsigned short ulo = f2bf(u - bf2f(uhi));
    ofr[0 * 3072 + idx] = whi;
    ofr[1 * 3072 + idx] = wlo;
    ofr[2 * 3072 + idx] = uhi;
    ofr[3 * 3072 + idx] = ulo;
}

// ---------- once per launch: readout R1/R2 -> MFMA B-frags (hi/lo) ----------
__global__ __launch_bounds__(256) void rprep_kernel(const float* __restrict__ R1,
                                                    const float* __restrict__ R2,
                                                    unsigned short* __restrict__ rfr)
{
    int idx = blockIdx.x * 256 + threadIdx.x;
    if (idx >= 8192 + 65536) return;
    if (idx < 8192) {
        int j = idx & 7, lane = (idx >> 3) & 63, g = idx >> 9;
        int k = (lane >> 4) * 8 + j;
        int n = g * 16 + (lane & 15);
        float v = R1[k * 256 + n];
        unsigned short hi = f2bf(v);
        rfr[idx] = hi;
        rfr[8192 + idx] = f2bf(v - bf2f(hi));
    } else {
        int idx2 = idx - 8192;
        int j = idx2 & 7, lane = (idx2 >> 3) & 63, tile = idx2 >> 9;
        int c = tile >> 4, g = tile & 15;
        int k = c * 32 + (lane >> 4) * 8 + j;
        int n = g * 16 + (lane & 15);
        float v = R2[k * 256 + n];
        unsigned short hi = f2bf(v);
        rfr[16384 + idx2] = hi;
        rfr[16384 + 65536 + idx2] = f2bf(v - bf2f(hi));
    }
}

// ---------- shared device body: 5-hop MFMA path GRU for one 16-path tile ----
// T = wave-private LDS (>= 16*36 floats). Result: hA = final h (A-row layout).
template <bool STORE_M>
__device__ __forceinline__ void path_gru_body(
    int p, int l15, int quad, float* T,
    const int* __restrict__ links,
    const unsigned short* __restrict__ wfr,
    const float* __restrict__ bp,
    const unsigned short* __restrict__ ls_hi,
    const unsigned short* __restrict__ ls_lo,
    const int* __restrict__ slot,
    const float* __restrict__ path_state,
    float* __restrict__ m,
    float (&hA)[8])
{
    int lane = quad * 16 + l15;
    int lk[PLEN];
    #pragma unroll
    for (int l = 0; l < PLEN; ++l) lk[l] = links[p * PLEN + l];
    bf16x8 pxh[PLEN], pxl[PLEN];
    #pragma unroll
    for (int l = 0; l < PLEN; ++l) {
        FragCast ch, cl;
        ch.u = *(const uint4*)(ls_hi + (size_t)lk[l] * DIM + quad * 8);
        cl.u = *(const uint4*)(ls_lo + (size_t)lk[l] * DIM + quad * 8);
        pxh[l] = ch.v; pxl[l] = cl.v;
    }
    int sl[PLEN];
    if (STORE_M) {
        #pragma unroll
        for (int l = 0; l < PLEN; ++l) sl[l] = slot[p * PLEN + l];
    }

    bf16x8 Wh[6], Wl[6], Uh[6], Ul[6];
    {
        const uint4* base = (const uint4*)wfr;
        #pragma unroll
        for (int g = 0; g < 6; ++g) {
            FragCast a;
            a.u = base[0 * 384 + g * 64 + lane]; Wh[g] = a.v;
            a.u = base[1 * 384 + g * 64 + lane]; Wl[g] = a.v;
            a.u = base[2 * 384 + g * 64 + lane]; Uh[g] = a.v;
            a.u = base[3 * 384 + g * 64 + lane]; Ul[g] = a.v;
        }
    }
    float bz[2], br[2], bnx[2], bnh[2];
    #pragma unroll
    for (int hf = 0; hf < 2; ++hf) {
        int c = hf * 16 + l15;
        bz[hf]  = bp[c]      + bp[96 + c];
        br[hf]  = bp[32 + c] + bp[96 + 32 + c];
        bnx[hf] = bp[64 + c];
        bnh[hf] = bp[96 + 64 + c];
    }

    {
        const float4* src = (const float4*)(path_state + (size_t)p * DIM + quad * 8);
        float4 v0 = src[0], v1 = src[1];
        hA[0]=v0.x; hA[1]=v0.y; hA[2]=v0.z; hA[3]=v0.w;
        hA[4]=v1.x; hA[5]=v1.y; hA[6]=v1.z; hA[7]=v1.w;
    }
    #pragma unroll
    for (int j = 0; j < 8; ++j) T[l15 * 36 + quad * 8 + j] = hA[j];
    __asm__ volatile("s_waitcnt lgkmcnt(0)" ::: "memory");
    float hC[2][4];
    #pragma unroll
    for (int hf = 0; hf < 2; ++hf)
        #pragma unroll
        for (int rg = 0; rg < 4; ++rg)
            hC[hf][rg] = T[(quad * 4 + rg) * 36 + hf * 16 + l15];

    bf16x8 ah, al;
    split_bf16(hA, ah, al);

    #pragma unroll
    for (int l = 0; l < PLEN; ++l) {
        bf16x8 xh = pxh[l], xl = pxl[l];
        #pragma unroll
        for (int hf = 0; hf < 2; ++hf) {
            f32x4 az = {0.f,0.f,0.f,0.f}, ar = {0.f,0.f,0.f,0.f};
            f32x4 axn = {0.f,0.f,0.f,0.f}, ahg = {0.f,0.f,0.f,0.f};
            int gz = hf, gr = 2 + hf, gn = 4 + hf;
            az = __builtin_amdgcn_mfma_f32_16x16x32_bf16(xh, Wh[gz], az, 0, 0, 0);
            az = __builtin_amdgcn_mfma_f32_16x16x32_bf16(xh, Wl[gz], az, 0, 0, 0);
            az = __builtin_amdgcn_mfma_f32_16x16x32_bf16(xl, Wh[gz], az, 0, 0, 0);
            az = __builtin_amdgcn_mfma_f32_16x16x32_bf16(ah, Uh[gz], az, 0, 0, 0);
            az = __builtin_amdgcn_mfma_f32_16x16x32_bf16(ah, Ul[gz], az, 0, 0, 0);
            az = __builtin_amdgcn_mfma_f32_16x16x32_bf16(al, Uh[gz], az, 0, 0, 0);
            ar = __builtin_amdgcn_mfma_f32_16x16x32_bf16(xh, Wh[gr], ar, 0, 0, 0);
            ar = __builtin_amdgcn_mfma_f32_16x16x32_bf16(xh, Wl[gr], ar, 0, 0, 0);
            ar = __builtin_amdgcn_mfma_f32_16x16x32_bf16(xl, Wh[gr], ar, 0, 0, 0);
            ar = __builtin_amdgcn_mfma_f32_16x16x32_bf16(ah, Uh[gr], ar, 0, 0, 0);
            ar = __builtin_amdgcn_mfma_f32_16x16x32_bf16(ah, Ul[gr], ar, 0, 0, 0);
            ar = __builtin_amdgcn_mfma_f32_16x16x32_bf16(al, Uh[gr], ar, 0, 0, 0);
            axn = __builtin_amdgcn_mfma_f32_16x16x32_bf16(xh, Wh[gn], axn, 0, 0, 0);
            axn = __builtin_amdgcn_mfma_f32_16x16x32_bf16(xh, Wl[gn], axn, 0, 0, 0);
            axn = __builtin_amdgcn_mfma_f32_16x16x32_bf16(xl, Wh[gn], axn, 0, 0, 0);
            ahg = __builtin_amdgcn_mfma_f32_16x16x32_bf16(ah, Uh[gn], ahg, 0, 0, 0);
            ahg = __builtin_amdgcn_mfma_f32_16x16x32_bf16(ah, Ul[gn], ahg, 0, 0, 0);
            ahg = __builtin_amdgcn_mfma_f32_16x16x32_bf16(al, Uh[gn], ahg, 0, 0, 0);
            #pragma unroll
            for (int rg = 0; rg < 4; ++rg) {
                float z  = fast_sigmoid(az[rg] + bz[hf]);
                float r  = fast_sigmoid(ar[rg] + br[hf]);
                float hn = fast_tanh(axn[rg] + bnx[hf] + r * (ahg[rg] + bnh[hf]));
                hC[hf][rg] = z * hC[hf][rg] + (1.0f - z) * hn;
            }
        }

        __asm__ volatile("s_waitcnt lgkmcnt(0)" ::: "memory");
        #pragma unroll
        for (int hf = 0; hf < 2; ++hf)
            #pragma unroll
            for (int rg = 0; rg < 4; ++rg)
                T[(quad * 4 + rg) * 36 + hf * 16 + l15] = hC[hf][rg];
        __asm__ volatile("s_waitcnt lgkmcnt(0)" ::: "memory");
        {
            const float4* rd = (const float4*)(T + l15 * 36 + quad * 8);
            float4 v0 = rd[0], v1 = rd[1];
            hA[0]=v0.x; hA[1]=v0.y; hA[2]=v0.z; hA[3]=v0.w;
            hA[4]=v1.x; hA[5]=v1.y; hA[6]=v1.z; hA[7]=v1.w;
        }
        if (STORE_M) {
            float4* dst = (float4*)(m + (size_t)sl[l] * DIM + quad * 8);
            float4 v0 = { hA[0], hA[1], hA[2], hA[3] };
            float4 v1 = { hA[4], hA[5], hA[6], hA[7] };
            dst[0] = v0; dst[1] = v1;
        }
        if (l < PLEN - 1) split_bf16(hA, ah, al);
    }
}

// ---------- MFMA path GRU kernel (iterations 0..6, stores m + path_state) ----
__global__ __launch_bounds__(256) void path_kernel(
    const int*   __restrict__ links,
    const unsigned short* __restrict__ wfr,
    const float* __restrict__ bp,
    const unsigned short* __restrict__ ls_hi,
    const unsigned short* __restrict__ ls_lo,
    const int*   __restrict__ slot,
    float* __restrict__ path_state,
    float* __restrict__ m)
{
    __shared__ __align__(16) float T4[4][16 * 36];
    int t = threadIdx.x;
    int wave = t >> 6, lane = t & 63;
    int l15 = lane & 15, quad = lane >> 4;
    int p0 = (blockIdx.x * 4 + wave) * 16;
    if (p0 >= NP) return;
    int p = p0 + l15;
    float hA[8];
    path_gru_body<true>(p, l15, quad, T4[wave], links, wfr, bp, ls_hi, ls_lo,
                        slot, path_state, m, hA);
    float4* ho = (float4*)(path_state + (size_t)p * DIM + quad * 8);
    float4 v0 = { hA[0], hA[1], hA[2], hA[3] };
    float4 v1 = { hA[4], hA[5], hA[6], hA[7] };
    ho[0] = v0; ho[1] = v1;
}

// ---------- fused aggregate + MFMA link GRU (R13-verified) ----------
__global__ __launch_bounds__(256) void aglk_kernel(
    const int* __restrict__ row_start,
    const float* __restrict__ m,
    const unsigned short* __restrict__ lfr,
    const float* __restrict__ bl,
    float* __restrict__ link_state,
    unsigned short* __restrict__ ls_hi, unsigned short* __restrict__ ls_lo)
{
    __shared__ __align__(16) float T4[4][16 * 36];
    int t = threadIdx.x;
    int wave = t >> 6, lane = t & 63;
    int l15 = lane & 15, quad = lane >> 4;
    int lb = (blockIdx.x * 4 + wave) * 16;
    if (lb >= NLINKS) return;
    float* T = T4[wave];
    int link = lb + l15;

    bf16x8 Wh[6], Wlo[6], Uh[6], Ulo[6];
    {
        const uint4* base = (const uint4*)lfr;
        #pragma unroll
        for (int g = 0; g < 6; ++g) {
            FragCast a;
            a.u = base[0 * 384 + g * 64 + lane]; Wh[g]  = a.v;
            a.u = base[1 * 384 + g * 64 + lane]; Wlo[g] = a.v;
            a.u = base[2 * 384 + g * 64 + lane]; Uh[g]  = a.v;
            a.u = base[3 * 384 + g * 64 + lane]; Ulo[g] = a.v;
        }
    }
    float bz[2], br[2], bnx[2], bnh[2];
    #pragma unroll
    for (int hf = 0; hf < 2; ++hf) {
        int c = hf * 16 + l15;
        bz[hf]  = bl[c]      + bl[96 + c];
        br[hf]  = bl[32 + c] + bl[96 + 32 + c];
        bnx[hf] = bl[64 + c];
        bnh[hf] = bl[96 + 64 + c];
    }

    int s0 = row_start[link], s1 = row_start[link + 1];
    float x8[8] = {0.f,0.f,0.f,0.f,0.f,0.f,0.f,0.f};
    int i = s0;
    for (; i + 4 <= s1; i += 4) {
        #pragma unroll
        for (int u = 0; u < 4; ++u) {
            const float4* mr = (const float4*)(m + (size_t)(i + u) * DIM + quad * 8);
            float4 a = mr[0], b = mr[1];
            x8[0] += a.x; x8[1] += a.y; x8[2] += a.z; x8[3] += a.w;
            x8[4] += b.x; x8[5] += b.y; x8[6] += b.z; x8[7] += b.w;
        }
    }
    for (; i < s1; ++i) {
        const float4* mr = (const float4*)(m + (size_t)i * DIM + quad * 8);
        float4 a = mr[0], b = mr[1];
        x8[0] += a.x; x8[1] += a.y; x8[2] += a.z; x8[3] += a.w;
        x8[4] += b.x; x8[5] += b.y; x8[6] += b.z; x8[7] += b.w;
    }
    bf16x8 xh, xl;
    split_bf16(x8, xh, xl);

    float hA[8];
    {
        const float4* src = (const float4*)(link_state + (size_t)link * DIM + quad * 8);
        float4 v0 = src[0], v1 = src[1];
        hA[0]=v0.x; hA[1]=v0.y; hA[2]=v0.z; hA[3]=v0.w;
        hA[4]=v1.x; hA[5]=v1.y; hA[6]=v1.z; hA[7]=v1.w;
    }
    #pragma unroll
    for (int j = 0; j < 8; ++j) T[l15 * 36 + quad * 8 + j] = hA[j];
    __asm__ volatile("s_waitcnt lgkmcnt(0)" ::: "memory");
    float hC[2][4];
    #pragma unroll
    for (int hf = 0; hf < 2; ++hf)
        #pragma unroll
        for (int rg = 0; rg < 4; ++rg)
            hC[hf][rg] = T[(quad * 4 + rg) * 36 + hf * 16 + l15];
    bf16x8 ah, al;
    split_bf16(hA, ah, al);

    #pragma unroll
    for (int hf = 0; hf < 2; ++hf) {
        f32x4 az = {0.f,0.f,0.f,0.f}, ar = {0.f,0.f,0.f,0.f};
        f32x4 axn = {0.f,0.f,0.f,0.f}, ahg = {0.f,0.f,0.f,0.f};
        int gz = hf, gr = 2 + hf, gn = 4 + hf;
        az = __builtin_amdgcn_mfma_f32_16x16x32_bf16(xh, Wh[gz],  az, 0, 0, 0);
        az = __builtin_amdgcn_mfma_f32_16x16x32_bf16(xh, Wlo[gz], az, 0, 0, 0);
        az = __builtin_amdgcn_mfma_f32_16x16x32_bf16(xl, Wh[gz],  az, 0, 0, 0);
        az = __builtin_amdgcn_mfma_f32_16x16x32_bf16(ah, Uh[gz],  az, 0, 0, 0);
        az = __builtin_amdgcn_mfma_f32_16x16x32_bf16(ah, Ulo[gz], az, 0, 0, 0);
        az = __builtin_amdgcn_mfma_f32_16x16x32_bf16(al, Uh[gz],  az, 0, 0, 0);
        ar = __builtin_amdgcn_mfma_f32_16x16x32_bf16(xh, Wh[gr],  ar, 0, 0, 0);
        ar = __builtin_amdgcn_mfma_f32_16x16x32_bf16(xh, Wlo[gr], ar, 0, 0, 0);
        ar = __builtin_amdgcn_mfma_f32_16x16x32_bf16(xl, Wh[gr],  ar, 0, 0, 0);
        ar = __builtin_amdgcn_mfma_f32_16x16x32_bf16(ah, Uh[gr],  ar, 0, 0, 0);
        ar = __builtin_amdgcn_mfma_f32_16x16x32_bf16(ah, Ulo[gr], ar, 0, 0, 0);
        ar = __builtin_amdgcn_mfma_f32_16x16x32_bf16(al, Uh[gr],  ar, 0, 0, 0);
        axn = __builtin_amdgcn_mfma_f32_16x16x32_bf16(xh, Wh[gn],  axn, 0, 0, 0);
        axn = __builtin_amdgcn_mfma_f32_16x16x32_bf16(xh, Wlo[gn], axn, 0, 0, 0);
        axn = __builtin_amdgcn_mfma_f32_16x16x32_bf16(xl, Wh[gn],  axn, 0, 0, 0);
        ahg = __builtin_amdgcn_mfma_f32_16x16x32_bf16(ah, Uh[gn],  ahg, 0, 0, 0);
        ahg = __builtin_amdgcn_mfma_f32_16x16x32_bf16(ah, Ulo[gn], ahg, 0, 0, 0);
        ahg = __builtin_amdgcn_mfma_f32_16x16x32_bf16(al, Uh[gn],  ahg, 0, 0, 0);
        #pragma unroll
        for (int rg = 0; rg < 4; ++rg) {
            float z  = fast_sigmoid(az[rg] + bz[hf]);
            float r  = fast_sigmoid(ar[rg] + br[hf]);
            float hn = fast_tanh(axn[rg] + bnx[hf] + r * (ahg[rg] + bnh[hf]));
            hC[hf][rg] = z * hC[hf][rg] + (1.0f - z) * hn;
        }
    }

    __asm__ volatile("s_waitcnt lgkmcnt(0)" ::: "memory");
    #pragma unroll
    for (int hf = 0; hf < 2; ++hf)
        #pragma unroll
        for (int rg = 0; rg < 4; ++rg)
            T[(quad * 4 + rg) * 36 + hf * 16 + l15] = hC[hf][rg];
    __asm__ volatile("s_waitcnt lgkmcnt(0)" ::: "memory");
    {
        const float4* rd = (const float4*)(T + l15 * 36 + quad * 8);
        float4 v0 = rd[0], v1 = rd[1];
        hA[0]=v0.x; hA[1]=v0.y; hA[2]=v0.z; hA[3]=v0.w;
        hA[4]=v1.x; hA[5]=v1.y; hA[6]=v1.z; hA[7]=v1.w;
    }
    float4* ho = (float4*)(link_state + (size_t)link * DIM + quad * 8);
    float4 v0 = { hA[0], hA[1], hA[2], hA[3] };
    float4 v1 = { hA[4], hA[5], hA[6], hA[7] };
    ho[0] = v0; ho[1] = v1;
    bf16x8 nh, nl;
    split_bf16(hA, nh, nl);
    FragCast ch, cl;
    ch.v = nh; cl.v = nl;
    *(uint4*)(ls_hi + (size_t)link * DIM + quad * 8) = ch.u;
    *(uint4*)(ls_lo + (size_t)link * DIM + quad * 8) = cl.u;
}

// ---------- fused: final path GRU iteration + MFMA readout ----------
__global__ __launch_bounds__(128, 1) void readout_kernel(
    const int*   __restrict__ links,
    const unsigned short* __restrict__ wfr,
    const float* __restrict__ bp,
    const unsigned short* __restrict__ ls_hi,
    const unsigned short* __restrict__ ls_lo,
    const float* __restrict__ path_state,
    const unsigned short* __restrict__ rfr,
    const float* __restrict__ Rb1, const float* __restrict__ Rb2,
    const float* __restrict__ R3,  const float* __restrict__ Rb3,
    float* __restrict__ out)
{
    __shared__ __align__(16) float T2[2][16 * 260];
    int t = threadIdx.x;
    int wave = t >> 6, lane = t & 63;
    int l15 = lane & 15, quad = lane >> 4;
    int p0 = (blockIdx.x * 2 + wave) * 16;
    if (p0 >= NP) return;
    float* T = T2[wave];
    int p = p0 + l15;

    float h0[8];
    path_gru_body<false>(p, l15, quad, T, links, wfr, bp, ls_hi, ls_lo,
                         nullptr, path_state, nullptr, h0);

    const uint4* r1h = (const uint4*)rfr;
    const uint4* r1l = r1h + 1024;
    const uint4* r2h = r1l + 1024;
    const uint4* r2l = r2h + 8192;

    bf16x8 a0h, a0l;
    split_bf16(h0, a0h, a0l);
    #pragma unroll 1
    for (int g = 0; g < 16; ++g) {
        FragCast bh, bl2;
        bh.u  = r1h[g * 64 + lane];
        bl2.u = r1l[g * 64 + lane];
        f32x4 c = {0.f,0.f,0.f,0.f};
        c = __builtin_amdgcn_mfma_f32_16x16x32_bf16(a0h, bh.v,  c, 0, 0, 0);
        c = __builtin_amdgcn_mfma_f32_16x16x32_bf16(a0h, bl2.v, c, 0, 0, 0);
        c = __builtin_amdgcn_mfma_f32_16x16x32_bf16(a0l, bh.v,  c, 0, 0, 0);
        float rb = Rb1[g * 16 + l15];
        #pragma unroll
        for (int rg = 0; rg < 4; ++rg)
            T[(quad * 4 + rg) * 260 + g * 16 + l15] = seluf(c[rg] + rb);
    }
    __asm__ volatile("s_waitcnt lgkmcnt(0)" ::: "memory");

    bf16x8 h1h[8], h1l[8];
    #pragma unroll
    for (int c = 0; c < 8; ++c) {
        float hv[8];
        const float4* rd = (const float4*)(T + l15 * 260 + c * 32 + quad * 8);
        float4 u0 = rd[0], u1 = rd[1];
        hv[0]=u0.x; hv[1]=u0.y; hv[2]=u0.z; hv[3]=u0.w;
        hv[4]=u1.x; hv[5]=u1.y; hv[6]=u1.z; hv[7]=u1.w;
        split_bf16(hv, h1h[c], h1l[c]);
    }

    float s[4] = {0.f, 0.f, 0.f, 0.f};
    #pragma unroll 1
    for (int g = 0; g < 16; ++g) {
        f32x4 acc = {0.f,0.f,0.f,0.f};
        #pragma unroll
        for (int c = 0; c < 8; ++c) {
            FragCast bh, bl2;
            bh.u  = r2h[(c * 16 + g) * 64 + lane];
            bl2.u = r2l[(c * 16 + g) * 64 + lane];
            acc = __builtin_amdgcn_mfma_f32_16x16x32_bf16(h1h[c], bh.v,  acc, 0, 0, 0);
            acc = __builtin_amdgcn_mfma_f32_16x16x32_bf16(h1h[c], bl2.v, acc, 0, 0, 0);
            acc = __builtin_amdgcn_mfma_f32_16x16x32_bf16(h1l[c], bh.v,  acc, 0, 0, 0);
        }
        float rb  = Rb2[g * 16 + l15];
        float r3v = R3[g * 16 + l15];
        #pragma unroll
        for (int rg = 0; rg < 4; ++rg)
            s[rg] += seluf(acc[rg] + rb) * r3v;
    }
    #pragma unroll
    for (int rg = 0; rg < 4; ++rg) {
        s[rg] += __shfl_xor(s[rg], 1);
        s[rg] += __shfl_xor(s[rg], 2);
        s[rg] += __shfl_xor(s[rg], 4);
        s[rg] += __shfl_xor(s[rg], 8);
    }
    if (l15 == 0) {
        float rb3 = Rb3[0];
        #pragma unroll
        for (int rg = 0; rg < 4; ++rg)
            out[p0 + quad * 4 + rg] = s[rg] + rb3;
    }
}

extern "C" void kernel_launch(void* const* d_in, const int* in_sizes, int n_in,
                              void* d_out, int out_size, void* d_ws, size_t ws_size,
                              hipStream_t stream)
{
    const int*   links = (const int*)d_in[0];
    const float* cap = (const float*)d_in[3];
    const float* pol = (const float*)d_in[4];
    const float* wts = (const float*)d_in[5];
    const float* bw  = (const float*)d_in[6];
    const float* tos = (const float*)d_in[7];
    const float* pk  = (const float*)d_in[8];
    const float* avg = (const float*)d_in[9];
    const float* Wp  = (const float*)d_in[10];
    const float* Up  = (const float*)d_in[11];
    const float* bp  = (const float*)d_in[12];
    const float* Wl  = (const float*)d_in[13];
    const float* Ul  = (const float*)d_in[14];
    const float* bl  = (const float*)d_in[15];
    const float* R1  = (const float*)d_in[16];
    const float* Rb1 = (const float*)d_in[17];
    const float* R2  = (const float*)d_in[18];
    const float* Rb2 = (const float*)d_in[19];
    const float* R3  = (const float*)d_in[20];
    const float* Rb3 = (const float*)d_in[21];

    char* w = (char*)d_ws;
    size_t off = 0;
    auto alloc = [&](size_t bytes) {
        char* p = w + off;
        off += (bytes + 255) & ~(size_t)255;
        return p;
    };
    float*          path_state = (float*)alloc((size_t)NP * DIM * 4);
    float*          link_state = (float*)alloc((size_t)NLINKS * DIM * 4);
    float*          m          = (float*)alloc((size_t)E_TOT * DIM * 4);
    unsigned short* ls_hi      = (unsigned short*)alloc((size_t)NLINKS * DIM * 2);
    unsigned short* ls_lo      = (unsigned short*)alloc((size_t)NLINKS * DIM * 2);
    unsigned short* wfr        = (unsigned short*)alloc(4 * 3072 * 2);
    unsigned short* lfr        = (unsigned short*)alloc(4 * 3072 * 2);
    unsigned short* rfr        = (unsigned short*)alloc((size_t)(8192 + 65536) * 2 * 2);
    int*            cnt        = (int*)alloc((size_t)NLINKS * 4);
    int*            row_start  = (int*)alloc((size_t)(NLINKS + 1) * 4);
    int*            cursor     = (int*)alloc((size_t)NLINKS * 4);
    int*            slot       = (int*)alloc((size_t)E_TOT * 4);

    init_kernel<<<(NP + 255) / 256, 256, 0, stream>>>(cap, pol, wts, bw, tos, pk, avg,
                                                      link_state, path_state, ls_hi, ls_lo);
    hipMemsetAsync(cnt, 0, (size_t)NLINKS * 4, stream);
    csr_count  <<<(E_TOT + 255) / 256, 256, 0, stream>>>(links, cnt);
    csr_scan   <<<1, 256, 0, stream>>>(cnt, row_start, cursor);
    csr_scatter<<<(E_TOT + 255) / 256, 256, 0, stream>>>(links, cursor, slot);
    wprep_kernel<<<12, 256, 0, stream>>>(Wp, Up, wfr);
    wprep_kernel<<<12, 256, 0, stream>>>(Wl, Ul, lfr);
    rprep_kernel<<<(8192 + 65536 + 255) / 256, 256, 0, stream>>>(R1, R2, rfr);

    const int PGRID = (NP / 16 + 3) / 4;
    const int LGRID = (NLINKS / 16 + 3) / 4;
    for (int it = 0; it < TITERS - 1; ++it) {
        path_kernel<<<PGRID, 256, 0, stream>>>(links, wfr, bp, ls_hi, ls_lo,
                                               slot, path_state, m);
        aglk_kernel<<<LGRID, 256, 0, stream>>>(row_start, m, lfr, bl,
                                               link_state, ls_hi, ls_lo);
    }
    // final path iteration fused into readout
    readout_kernel<<<(NP / 16 + 1) / 2, 128, 0, stream>>>(links, wfr, bp, ls_hi, ls_lo,
                                                          path_state, rfr, Rb1, Rb2,
                                                          R3, Rb3, (float*)d_out);
}

// Round 19
// 806.831 us; speedup vs baseline: 1.3827x; 1.0146x over previous
//
#include <hip/hip_runtime.h>
#include <hip/hip_bf16.h>

#define NP     100000   // n_paths
#define PLEN   5        // path length
#define NLINKS 10000    // n_links
#define DIM    32       // state dim
#define TITERS 8        // message passing iterations
#define E_TOT  (NP * PLEN)

using bf16x8 = __attribute__((ext_vector_type(8))) short;
using f32x4  = __attribute__((ext_vector_type(4))) float;
union FragCast { uint4 u; bf16x8 v; };

// ---------- helpers ----------
__device__ __forceinline__ float fast_sigmoid(float v) {
    return 1.0f / (1.0f + __expf(-v));
}
__device__ __forceinline__ float fast_tanh(float v) {
    float e = __expf(-2.0f * fabsf(v));
    float t = (1.0f - e) / (1.0f + e);
    return v >= 0.0f ? t : -t;
}
__device__ __forceinline__ float seluf(float v) {
    const float sc = 1.0507009873554805f;
    const float al = 1.6732632423543772f;
    return v > 0.0f ? sc * v : sc * al * (__expf(v) - 1.0f);
}
__device__ __forceinline__ unsigned short f2bf(float f) {
    union { float f; unsigned u; } c; c.f = f;
    unsigned u = c.u;
    return (unsigned short)((u + 0x7fffu + ((u >> 16) & 1u)) >> 16);
}
__device__ __forceinline__ float bf2f(unsigned short b) {
    union { unsigned u; float f; } c; c.u = ((unsigned)b) << 16;
    return c.f;
}
__device__ __forceinline__ void split_bf16(const float (&v)[8], bf16x8& hi, bf16x8& lo) {
    unsigned uh[4], ul[4];
    #pragma unroll
    for (int i = 0; i < 4; ++i) {
        unsigned short h0 = f2bf(v[2*i]),   h1 = f2bf(v[2*i+1]);
        float r0 = v[2*i] - bf2f(h0),       r1 = v[2*i+1] - bf2f(h1);
        unsigned short l0 = f2bf(r0),       l1 = f2bf(r1);
        uh[i] = (unsigned)h0 | ((unsigned)h1 << 16);
        ul[i] = (unsigned)l0 | ((unsigned)l1 << 16);
    }
    FragCast ch, cl;
    ch.u.x = uh[0]; ch.u.y = uh[1]; ch.u.z = uh[2]; ch.u.w = uh[3];
    cl.u.x = ul[0]; cl.u.y = ul[1]; cl.u.z = ul[2]; cl.u.w = ul[3];
    hi = ch.v; lo = cl.v;
}

// ---------- init + CSR count (merged: disjoint work, one dispatch) ----------
// grid covers E_TOT; i<NLINKS does link init, i<NP path init, i<E_TOT count.
__global__ __launch_bounds__(256) void init_kernel(
    const int*   __restrict__ links,
    const float* __restrict__ cap, const float* __restrict__ pol, const float* __restrict__ wts,
    const float* __restrict__ bw,  const float* __restrict__ tos,
    const float* __restrict__ pk,  const float* __restrict__ avg,
    float* __restrict__ link_state, float* __restrict__ path_state,
    unsigned short* __restrict__ ls_hi, unsigned short* __restrict__ ls_lo,
    int* __restrict__ cnt)
{
    int i = blockIdx.x * 256 + threadIdx.x;
    if (i < E_TOT) atomicAdd(&cnt[links[i]], 1);
    if (i < NLINKS) {
        float row[DIM];
        #pragma unroll
        for (int c = 0; c < DIM; ++c) row[c] = 0.0f;
        row[0] = cap[i]; row[1] = pol[i]; row[2] = wts[i];
        float4* o = (float4*)(link_state + (size_t)i * DIM);
        #pragma unroll
        for (int c = 0; c < 8; ++c) {
            float4 v = { row[4*c], row[4*c+1], row[4*c+2], row[4*c+3] };
            o[c] = v;
        }
        unsigned ush[16], usl[16];
        #pragma unroll
        for (int c = 0; c < 16; ++c) {
            unsigned short h0 = f2bf(row[2*c]), h1 = f2bf(row[2*c+1]);
            unsigned short l0 = f2bf(row[2*c] - bf2f(h0));
            unsigned short l1 = f2bf(row[2*c+1] - bf2f(h1));
            ush[c] = (unsigned)h0 | ((unsigned)h1 << 16);
            usl[c] = (unsigned)l0 | ((unsigned)l1 << 16);
        }
        uint4* oh = (uint4*)(ls_hi + (size_t)i * DIM);
        uint4* ol = (uint4*)(ls_lo + (size_t)i * DIM);
        #pragma unroll
        for (int q = 0; q < 4; ++q) {
            uint4 vh = { ush[4*q], ush[4*q+1], ush[4*q+2], ush[4*q+3] };
            uint4 vl = { usl[4*q], usl[4*q+1], usl[4*q+2], usl[4*q+3] };
            oh[q] = vh; ol[q] = vl;
        }
    }
    if (i < NP) {
        float row[DIM];
        #pragma unroll
        for (int c = 0; c < DIM; ++c) row[c] = 0.0f;
        row[0] = bw[i]; row[1] = tos[i]; row[2] = pk[i]; row[3] = avg[i];
        float4* o = (float4*)(path_state + (size_t)i * DIM);
        #pragma unroll
        for (int c = 0; c < 8; ++c) {
            float4 v = { row[4*c], row[4*c+1], row[4*c+2], row[4*c+3] };
            o[c] = v;
        }
    }
}

// ---------- prep item helpers ----------
__device__ __forceinline__ void wprep_item(const float* __restrict__ W,
                                           const float* __restrict__ U,
                                           unsigned short* __restrict__ ofr, int idx)
{
    int j = idx & 7, lane = (idx >> 3) & 63, g = idx >> 9;
    int k = (lane >> 4) * 8 + j;
    int n = g * 16 + (lane & 15);
    float w = W[k * 96 + n];
    float u = U[k * 96 + n];
    unsigned short whi = f2bf(w); unsigned short wlo = f2bf(w - bf2f(whi));
    unsigned short uhi = f2bf(u); unsigned short ulo = f2bf(u - bf2f(uhi));
    ofr[0 * 3072 + idx] = whi;
    ofr[1 * 3072 + idx] = wlo;
    ofr[2 * 3072 + idx] = uhi;
    ofr[3 * 3072 + idx] = ulo;
}

__device__ __forceinline__ void rprep_item(const float* __restrict__ R1,
                                           const float* __restrict__ R2,
                                           unsigned short* __restrict__ rfr, int idx)
{
    if (idx < 8192) {
        int j = idx & 7, lane = (idx >> 3) & 63, g = idx >> 9;
        int k = (lane >> 4) * 8 + j;
        int n = g * 16 + (lane & 15);
        float v = R1[k * 256 + n];
        unsigned short hi = f2bf(v);
        rfr[idx] = hi;
        rfr[8192 + idx] = f2bf(v - bf2f(hi));
    } else {
        int idx2 = idx - 8192;
        int j = idx2 & 7, lane = (idx2 >> 3) & 63, tile = idx2 >> 9;
        int c = tile >> 4, g = tile & 15;
        int k = c * 32 + (lane >> 4) * 8 + j;
        int n = g * 16 + (lane & 15);
        float v = R2[k * 256 + n];
        unsigned short hi = f2bf(v);
        rfr[16384 + idx2] = hi;
        rfr[16384 + 65536 + idx2] = f2bf(v - bf2f(hi));
    }
}

// ---------- merged prep: block 0 = CSR scan; blocks 1.. = weight frag prep ----
// (scan reads cnt from the prior dispatch; wprep/rprep are input-only: no
// intra-kernel dependencies)
__global__ __launch_bounds__(256) void prep_kernel(
    const int*   __restrict__ cnt,
    int* __restrict__ row_start, int* __restrict__ cursor,
    const float* __restrict__ Wp, const float* __restrict__ Up,
    unsigned short* __restrict__ wfr,
    const float* __restrict__ Wl, const float* __restrict__ Ul,
    unsigned short* __restrict__ lfr,
    const float* __restrict__ R1, const float* __restrict__ R2,
    unsigned short* __restrict__ rfr)
{
    int t = threadIdx.x;
    if (blockIdx.x == 0) {
        // 2-pass chunked scan
        __shared__ int s[256];
        const int CH = (NLINKS + 255) / 256;   // 40
        int base = t * CH;
        int sum = 0;
        for (int i = 0; i < CH; ++i) {
            int idx = base + i;
            if (idx < NLINKS) sum += cnt[idx];
        }
        s[t] = sum;
        __syncthreads();
        for (int off = 1; off < 256; off <<= 1) {
            int v = (t >= off) ? s[t - off] : 0;
            __syncthreads();
            s[t] += v;
            __syncthreads();
        }
        int run = s[t] - sum;
        for (int i = 0; i < CH; ++i) {
            int idx = base + i;
            if (idx < NLINKS) {
                row_start[idx] = run;
                cursor[idx]    = run;
                run += cnt[idx];
            }
        }
        if (t == 255) row_start[NLINKS] = s[255];
        return;
    }
    int idx = (blockIdx.x - 1) * 256 + t;
    if (idx < 3072) {
        wprep_item(Wp, Up, wfr, idx);
    } else if (idx < 6144) {
        wprep_item(Wl, Ul, lfr, idx - 3072);
    } else if (idx < 6144 + 8192 + 65536) {
        rprep_item(R1, R2, rfr, idx - 6144);
    }
}

__global__ __launch_bounds__(256) void csr_scatter(const int* __restrict__ links,
                                                   int* __restrict__ cursor,
                                                   int* __restrict__ slot)
{
    int e = blockIdx.x * 256 + threadIdx.x;
    if (e < E_TOT) slot[e] = atomicAdd(&cursor[links[e]], 1);
}

// ---------- shared device body: 5-hop MFMA path GRU for one 16-path tile ----
template <bool STORE_M>
__device__ __forceinline__ void path_gru_body(
    int p, int l15, int quad, float* T,
    const int* __restrict__ links,
    const unsigned short* __restrict__ wfr,
    const float* __restrict__ bp,
    const unsigned short* __restrict__ ls_hi,
    const unsigned short* __restrict__ ls_lo,
    const int* __restrict__ slot,
    const float* __restrict__ path_state,
    float* __restrict__ m,
    float (&hA)[8])
{
    int lane = quad * 16 + l15;
    int lk[PLEN];
    #pragma unroll
    for (int l = 0; l < PLEN; ++l) lk[l] = links[p * PLEN + l];
    bf16x8 pxh[PLEN], pxl[PLEN];
    #pragma unroll
    for (int l = 0; l < PLEN; ++l) {
        FragCast ch, cl;
        ch.u = *(const uint4*)(ls_hi + (size_t)lk[l] * DIM + quad * 8);
        cl.u = *(const uint4*)(ls_lo + (size_t)lk[l] * DIM + quad * 8);
        pxh[l] = ch.v; pxl[l] = cl.v;
    }
    int sl[PLEN];
    if (STORE_M) {
        #pragma unroll
        for (int l = 0; l < PLEN; ++l) sl[l] = slot[p * PLEN + l];
    }

    bf16x8 Wh[6], Wl[6], Uh[6], Ul[6];
    {
        const uint4* base = (const uint4*)wfr;
        #pragma unroll
        for (int g = 0; g < 6; ++g) {
            FragCast a;
            a.u = base[0 * 384 + g * 64 + lane]; Wh[g] = a.v;
            a.u = base[1 * 384 + g * 64 + lane]; Wl[g] = a.v;
            a.u = base[2 * 384 + g * 64 + lane]; Uh[g] = a.v;
            a.u = base[3 * 384 + g * 64 + lane]; Ul[g] = a.v;
        }
    }
    float bz[2], br[2], bnx[2], bnh[2];
    #pragma unroll
    for (int hf = 0; hf < 2; ++hf) {
        int c = hf * 16 + l15;
        bz[hf]  = bp[c]      + bp[96 + c];
        br[hf]  = bp[32 + c] + bp[96 + 32 + c];
        bnx[hf] = bp[64 + c];
        bnh[hf] = bp[96 + 64 + c];
    }

    {
        const float4* src = (const float4*)(path_state + (size_t)p * DIM + quad * 8);
        float4 v0 = src[0], v1 = src[1];
        hA[0]=v0.x; hA[1]=v0.y; hA[2]=v0.z; hA[3]=v0.w;
        hA[4]=v1.x; hA[5]=v1.y; hA[6]=v1.z; hA[7]=v1.w;
    }
    #pragma unroll
    for (int j = 0; j < 8; ++j) T[l15 * 36 + quad * 8 + j] = hA[j];
    __asm__ volatile("s_waitcnt lgkmcnt(0)" ::: "memory");
    float hC[2][4];
    #pragma unroll
    for (int hf = 0; hf < 2; ++hf)
        #pragma unroll
        for (int rg = 0; rg < 4; ++rg)
            hC[hf][rg] = T[(quad * 4 + rg) * 36 + hf * 16 + l15];

    bf16x8 ah, al;
    split_bf16(hA, ah, al);

    #pragma unroll
    for (int l = 0; l < PLEN; ++l) {
        bf16x8 xh = pxh[l], xl = pxl[l];
        #pragma unroll
        for (int hf = 0; hf < 2; ++hf) {
            f32x4 az = {0.f,0.f,0.f,0.f}, ar = {0.f,0.f,0.f,0.f};
            f32x4 axn = {0.f,0.f,0.f,0.f}, ahg = {0.f,0.f,0.f,0.f};
            int gz = hf, gr = 2 + hf, gn = 4 + hf;
            az = __builtin_amdgcn_mfma_f32_16x16x32_bf16(xh, Wh[gz], az, 0, 0, 0);
            az = __builtin_amdgcn_mfma_f32_16x16x32_bf16(xh, Wl[gz], az, 0, 0, 0);
            az = __builtin_amdgcn_mfma_f32_16x16x32_bf16(xl, Wh[gz], az, 0, 0, 0);
            az = __builtin_amdgcn_mfma_f32_16x16x32_bf16(ah, Uh[gz], az, 0, 0, 0);
            az = __builtin_amdgcn_mfma_f32_16x16x32_bf16(ah, Ul[gz], az, 0, 0, 0);
            az = __builtin_amdgcn_mfma_f32_16x16x32_bf16(al, Uh[gz], az, 0, 0, 0);
            ar = __builtin_amdgcn_mfma_f32_16x16x32_bf16(xh, Wh[gr], ar, 0, 0, 0);
            ar = __builtin_amdgcn_mfma_f32_16x16x32_bf16(xh, Wl[gr], ar, 0, 0, 0);
            ar = __builtin_amdgcn_mfma_f32_16x16x32_bf16(xl, Wh[gr], ar, 0, 0, 0);
            ar = __builtin_amdgcn_mfma_f32_16x16x32_bf16(ah, Uh[gr], ar, 0, 0, 0);
            ar = __builtin_amdgcn_mfma_f32_16x16x32_bf16(ah, Ul[gr], ar, 0, 0, 0);
            ar = __builtin_amdgcn_mfma_f32_16x16x32_bf16(al, Uh[gr], ar, 0, 0, 0);
            axn = __builtin_amdgcn_mfma_f32_16x16x32_bf16(xh, Wh[gn], axn, 0, 0, 0);
            axn = __builtin_amdgcn_mfma_f32_16x16x32_bf16(xh, Wl[gn], axn, 0, 0, 0);
            axn = __builtin_amdgcn_mfma_f32_16x16x32_bf16(xl, Wh[gn], axn, 0, 0, 0);
            ahg = __builtin_amdgcn_mfma_f32_16x16x32_bf16(ah, Uh[gn], ahg, 0, 0, 0);
            ahg = __builtin_amdgcn_mfma_f32_16x16x32_bf16(ah, Ul[gn], ahg, 0, 0, 0);
            ahg = __builtin_amdgcn_mfma_f32_16x16x32_bf16(al, Uh[gn], ahg, 0, 0, 0);
            #pragma unroll
            for (int rg = 0; rg < 4; ++rg) {
                float z  = fast_sigmoid(az[rg] + bz[hf]);
                float r  = fast_sigmoid(ar[rg] + br[hf]);
                float hn = fast_tanh(axn[rg] + bnx[hf] + r * (ahg[rg] + bnh[hf]));
                hC[hf][rg] = z * hC[hf][rg] + (1.0f - z) * hn;
            }
        }

        __asm__ volatile("s_waitcnt lgkmcnt(0)" ::: "memory");
        #pragma unroll
        for (int hf = 0; hf < 2; ++hf)
            #pragma unroll
            for (int rg = 0; rg < 4; ++rg)
                T[(quad * 4 + rg) * 36 + hf * 16 + l15] = hC[hf][rg];
        __asm__ volatile("s_waitcnt lgkmcnt(0)" ::: "memory");
        {
            const float4* rd = (const float4*)(T + l15 * 36 + quad * 8);
            float4 v0 = rd[0], v1 = rd[1];
            hA[0]=v0.x; hA[1]=v0.y; hA[2]=v0.z; hA[3]=v0.w;
            hA[4]=v1.x; hA[5]=v1.y; hA[6]=v1.z; hA[7]=v1.w;
        }
        if (STORE_M) {
            float4* dst = (float4*)(m + (size_t)sl[l] * DIM + quad * 8);
            float4 v0 = { hA[0], hA[1], hA[2], hA[3] };
            float4 v1 = { hA[4], hA[5], hA[6], hA[7] };
            dst[0] = v0; dst[1] = v1;
        }
        if (l < PLEN - 1) split_bf16(hA, ah, al);
    }
}

// ---------- MFMA path GRU kernel (iterations 0..6) ----------
__global__ __launch_bounds__(256) void path_kernel(
    const int*   __restrict__ links,
    const unsigned short* __restrict__ wfr,
    const float* __restrict__ bp,
    const unsigned short* __restrict__ ls_hi,
    const unsigned short* __restrict__ ls_lo,
    const int*   __restrict__ slot,
    float* __restrict__ path_state,
    float* __restrict__ m)
{
    __shared__ __align__(16) float T4[4][16 * 36];
    int t = threadIdx.x;
    int wave = t >> 6, lane = t & 63;
    int l15 = lane & 15, quad = lane >> 4;
    int p0 = (blockIdx.x * 4 + wave) * 16;
    if (p0 >= NP) return;
    int p = p0 + l15;
    float hA[8];
    path_gru_body<true>(p, l15, quad, T4[wave], links, wfr, bp, ls_hi, ls_lo,
                        slot, path_state, m, hA);
    float4* ho = (float4*)(path_state + (size_t)p * DIM + quad * 8);
    float4 v0 = { hA[0], hA[1], hA[2], hA[3] };
    float4 v1 = { hA[4], hA[5], hA[6], hA[7] };
    ho[0] = v0; ho[1] = v1;
}

// ---------- fused aggregate + MFMA link GRU ----------
__global__ __launch_bounds__(256) void aglk_kernel(
    const int* __restrict__ row_start,
    const float* __restrict__ m,
    const unsigned short* __restrict__ lfr,
    const float* __restrict__ bl,
    float* __restrict__ link_state,
    unsigned short* __restrict__ ls_hi, unsigned short* __restrict__ ls_lo)
{
    __shared__ __align__(16) float T4[4][16 * 36];
    int t = threadIdx.x;
    int wave = t >> 6, lane = t & 63;
    int l15 = lane & 15, quad = lane >> 4;
    int lb = (blockIdx.x * 4 + wave) * 16;
    if (lb >= NLINKS) return;
    float* T = T4[wave];
    int link = lb + l15;

    bf16x8 Wh[6], Wlo[6], Uh[6], Ulo[6];
    {
        const uint4* base = (const uint4*)lfr;
        #pragma unroll
        for (int g = 0; g < 6; ++g) {
            FragCast a;
            a.u = base[0 * 384 + g * 64 + lane]; Wh[g]  = a.v;
            a.u = base[1 * 384 + g * 64 + lane]; Wlo[g] = a.v;
            a.u = base[2 * 384 + g * 64 + lane]; Uh[g]  = a.v;
            a.u = base[3 * 384 + g * 64 + lane]; Ulo[g] = a.v;
        }
    }
    float bz[2], br[2], bnx[2], bnh[2];
    #pragma unroll
    for (int hf = 0; hf < 2; ++hf) {
        int c = hf * 16 + l15;
        bz[hf]  = bl[c]      + bl[96 + c];
        br[hf]  = bl[32 + c] + bl[96 + 32 + c];
        bnx[hf] = bl[64 + c];
        bnh[hf] = bl[96 + 64 + c];
    }

    int s0 = row_start[link], s1 = row_start[link + 1];
    float x8[8] = {0.f,0.f,0.f,0.f,0.f,0.f,0.f,0.f};
    int i = s0;
    for (; i + 4 <= s1; i += 4) {
        #pragma unroll
        for (int u = 0; u < 4; ++u) {
            const float4* mr = (const float4*)(m + (size_t)(i + u) * DIM + quad * 8);
            float4 a = mr[0], b = mr[1];
            x8[0] += a.x; x8[1] += a.y; x8[2] += a.z; x8[3] += a.w;
            x8[4] += b.x; x8[5] += b.y; x8[6] += b.z; x8[7] += b.w;
        }
    }
    for (; i < s1; ++i) {
        const float4* mr = (const float4*)(m + (size_t)i * DIM + quad * 8);
        float4 a = mr[0], b = mr[1];
        x8[0] += a.x; x8[1] += a.y; x8[2] += a.z; x8[3] += a.w;
        x8[4] += b.x; x8[5] += b.y; x8[6] += b.z; x8[7] += b.w;
    }
    bf16x8 xh, xl;
    split_bf16(x8, xh, xl);

    float hA[8];
    {
        const float4* src = (const float4*)(link_state + (size_t)link * DIM + quad * 8);
        float4 v0 = src[0], v1 = src[1];
        hA[0]=v0.x; hA[1]=v0.y; hA[2]=v0.z; hA[3]=v0.w;
        hA[4]=v1.x; hA[5]=v1.y; hA[6]=v1.z; hA[7]=v1.w;
    }
    #pragma unroll
    for (int j = 0; j < 8; ++j) T[l15 * 36 + quad * 8 + j] = hA[j];
    __asm__ volatile("s_waitcnt lgkmcnt(0)" ::: "memory");
    float hC[2][4];
    #pragma unroll
    for (int hf = 0; hf < 2; ++hf)
        #pragma unroll
        for (int rg = 0; rg < 4; ++rg)
            hC[hf][rg] = T[(quad * 4 + rg) * 36 + hf * 16 + l15];
    bf16x8 ah, al;
    split_bf16(hA, ah, al);

    #pragma unroll
    for (int hf = 0; hf < 2; ++hf) {
        f32x4 az = {0.f,0.f,0.f,0.f}, ar = {0.f,0.f,0.f,0.f};
        f32x4 axn = {0.f,0.f,0.f,0.f}, ahg = {0.f,0.f,0.f,0.f};
        int gz = hf, gr = 2 + hf, gn = 4 + hf;
        az = __builtin_amdgcn_mfma_f32_16x16x32_bf16(xh, Wh[gz],  az, 0, 0, 0);
        az = __builtin_amdgcn_mfma_f32_16x16x32_bf16(xh, Wlo[gz], az, 0, 0, 0);
        az = __builtin_amdgcn_mfma_f32_16x16x32_bf16(xl, Wh[gz],  az, 0, 0, 0);
        az = __builtin_amdgcn_mfma_f32_16x16x32_bf16(ah, Uh[gz],  az, 0, 0, 0);
        az = __builtin_amdgcn_mfma_f32_16x16x32_bf16(ah, Ulo[gz], az, 0, 0, 0);
        az = __builtin_amdgcn_mfma_f32_16x16x32_bf16(al, Uh[gz],  az, 0, 0, 0);
        ar = __builtin_amdgcn_mfma_f32_16x16x32_bf16(xh, Wh[gr],  ar, 0, 0, 0);
        ar = __builtin_amdgcn_mfma_f32_16x16x32_bf16(xh, Wlo[gr], ar, 0, 0, 0);
        ar = __builtin_amdgcn_mfma_f32_16x16x32_bf16(xl, Wh[gr],  ar, 0, 0, 0);
        ar = __builtin_amdgcn_mfma_f32_16x16x32_bf16(ah, Uh[gr],  ar, 0, 0, 0);
        ar = __builtin_amdgcn_mfma_f32_16x16x32_bf16(ah, Ulo[gr], ar, 0, 0, 0);
        ar = __builtin_amdgcn_mfma_f32_16x16x32_bf16(al, Uh[gr],  ar, 0, 0, 0);
        axn = __builtin_amdgcn_mfma_f32_16x16x32_bf16(xh, Wh[gn],  axn, 0, 0, 0);
        axn = __builtin_amdgcn_mfma_f32_16x16x32_bf16(xh, Wlo[gn], axn, 0, 0, 0);
        axn = __builtin_amdgcn_mfma_f32_16x16x32_bf16(xl, Wh[gn],  axn, 0, 0, 0);
        ahg = __builtin_amdgcn_mfma_f32_16x16x32_bf16(ah, Uh[gn],  ahg, 0, 0, 0);
        ahg = __builtin_amdgcn_mfma_f32_16x16x32_bf16(ah, Ulo[gn], ahg, 0, 0, 0);
        ahg = __builtin_amdgcn_mfma_f32_16x16x32_bf16(al, Uh[gn],  ahg, 0, 0, 0);
        #pragma unroll
        for (int rg = 0; rg < 4; ++rg) {
            float z  = fast_sigmoid(az[rg] + bz[hf]);
            float r  = fast_sigmoid(ar[rg] + br[hf]);
            float hn = fast_tanh(axn[rg] + bnx[hf] + r * (ahg[rg] + bnh[hf]));
            hC[hf][rg] = z * hC[hf][rg] + (1.0f - z) * hn;
        }
    }

    __asm__ volatile("s_waitcnt lgkmcnt(0)" ::: "memory");
    #pragma unroll
    for (int hf = 0; hf < 2; ++hf)
        #pragma unroll
        for (int rg = 0; rg < 4; ++rg)
            T[(quad * 4 + rg) * 36 + hf * 16 + l15] = hC[hf][rg];
    __asm__ volatile("s_waitcnt lgkmcnt(0)" ::: "memory");
    {
        const float4* rd = (const float4*)(T + l15 * 36 + quad * 8);
        float4 v0 = rd[0], v1 = rd[1];
        hA[0]=v0.x; hA[1]=v0.y; hA[2]=v0.z; hA[3]=v0.w;
        hA[4]=v1.x; hA[5]=v1.y; hA[6]=v1.z; hA[7]=v1.w;
    }
    float4* ho = (float4*)(link_state + (size_t)link * DIM + quad * 8);
    float4 v0 = { hA[0], hA[1], hA[2], hA[3] };
    float4 v1 = { hA[4], hA[5], hA[6], hA[7] };
    ho[0] = v0; ho[1] = v1;
    bf16x8 nh, nl;
    split_bf16(hA, nh, nl);
    FragCast ch, cl;
    ch.v = nh; cl.v = nl;
    *(uint4*)(ls_hi + (size_t)link * DIM + quad * 8) = ch.u;
    *(uint4*)(ls_lo + (size_t)link * DIM + quad * 8) = cl.u;
}

// ---------- fused: final path GRU iteration + MFMA readout ----------
__global__ __launch_bounds__(128, 1) void readout_kernel(
    const int*   __restrict__ links,
    const unsigned short* __restrict__ wfr,
    const float* __restrict__ bp,
    const unsigned short* __restrict__ ls_hi,
    const unsigned short* __restrict__ ls_lo,
    const float* __restrict__ path_state,
    const unsigned short* __restrict__ rfr,
    const float* __restrict__ Rb1, const float* __restrict__ Rb2,
    const float* __restrict__ R3,  const float* __restrict__ Rb3,
    float* __restrict__ out)
{
    __shared__ __align__(16) float T2[2][16 * 260];
    int t = threadIdx.x;
    int wave = t >> 6, lane = t & 63;
    int l15 = lane & 15, quad = lane >> 4;
    int p0 = (blockIdx.x * 2 + wave) * 16;
    if (p0 >= NP) return;
    float* T = T2[wave];
    int p = p0 + l15;

    float h0[8];
    path_gru_body<false>(p, l15, quad, T, links, wfr, bp, ls_hi, ls_lo,
                         nullptr, path_state, nullptr, h0);

    const uint4* r1h = (const uint4*)rfr;
    const uint4* r1l = r1h + 1024;
    const uint4* r2h = r1l + 1024;
    const uint4* r2l = r2h + 8192;

    bf16x8 a0h, a0l;
    split_bf16(h0, a0h, a0l);
    #pragma unroll 1
    for (int g = 0; g < 16; ++g) {
        FragCast bh, bl2;
        bh.u  = r1h[g * 64 + lane];
        bl2.u = r1l[g * 64 + lane];
        f32x4 c = {0.f,0.f,0.f,0.f};
        c = __builtin_amdgcn_mfma_f32_16x16x32_bf16(a0h, bh.v,  c, 0, 0, 0);
        c = __builtin_amdgcn_mfma_f32_16x16x32_bf16(a0h, bl2.v, c, 0, 0, 0);
        c = __builtin_amdgcn_mfma_f32_16x16x32_bf16(a0l, bh.v,  c, 0, 0, 0);
        float rb = Rb1[g * 16 + l15];
        #pragma unroll
        for (int rg = 0; rg < 4; ++rg)
            T[(quad * 4 + rg) * 260 + g * 16 + l15] = seluf(c[rg] + rb);
    }
    __asm__ volatile("s_waitcnt lgkmcnt(0)" ::: "memory");

    bf16x8 h1h[8], h1l[8];
    #pragma unroll
    for (int c = 0; c < 8; ++c) {
        float hv[8];
        const float4* rd = (const float4*)(T + l15 * 260 + c * 32 + quad * 8);
        float4 u0 = rd[0], u1 = rd[1];
        hv[0]=u0.x; hv[1]=u0.y; hv[2]=u0.z; hv[3]=u0.w;
        hv[4]=u1.x; hv[5]=u1.y; hv[6]=u1.z; hv[7]=u1.w;
        split_bf16(hv, h1h[c], h1l[c]);
    }

    float s[4] = {0.f, 0.f, 0.f, 0.f};
    #pragma unroll 1
    for (int g = 0; g < 16; ++g) {
        f32x4 acc = {0.f,0.f,0.f,0.f};
        #pragma unroll
        for (int c = 0; c < 8; ++c) {
            FragCast bh, bl2;
            bh.u  = r2h[(c * 16 + g) * 64 + lane];
            bl2.u = r2l[(c * 16 + g) * 64 + lane];
            acc = __builtin_amdgcn_mfma_f32_16x16x32_bf16(h1h[c], bh.v,  acc, 0, 0, 0);
            acc = __builtin_amdgcn_mfma_f32_16x16x32_bf16(h1h[c], bl2.v, acc, 0, 0, 0);
            acc = __builtin_amdgcn_mfma_f32_16x16x32_bf16(h1l[c], bh.v,  acc, 0, 0, 0);
        }
        float rb  = Rb2[g * 16 + l15];
        float r3v = R3[g * 16 + l15];
        #pragma unroll
        for (int rg = 0; rg < 4; ++rg)
            s[rg] += seluf(acc[rg] + rb) * r3v;
    }
    #pragma unroll
    for (int rg = 0; rg < 4; ++rg) {
        s[rg] += __shfl_xor(s[rg], 1);
        s[rg] += __shfl_xor(s[rg], 2);
        s[rg] += __shfl_xor(s[rg], 4);
        s[rg] += __shfl_xor(s[rg], 8);
    }
    if (l15 == 0) {
        float rb3 = Rb3[0];
        #pragma unroll
        for (int rg = 0; rg < 4; ++rg)
            out[p0 + quad * 4 + rg] = s[rg] + rb3;
    }
}

extern "C" void kernel_launch(void* const* d_in, const int* in_sizes, int n_in,
                              void* d_out, int out_size, void* d_ws, size_t ws_size,
                              hipStream_t stream)
{
    const int*   links = (const int*)d_in[0];
    const float* cap = (const float*)d_in[3];
    const float* pol = (const float*)d_in[4];
    const float* wts = (const float*)d_in[5];
    const float* bw  = (const float*)d_in[6];
    const float* tos = (const float*)d_in[7];
    const float* pk  = (const float*)d_in[8];
    const float* avg = (const float*)d_in[9];
    const float* Wp  = (const float*)d_in[10];
    const float* Up  = (const float*)d_in[11];
    const float* bp  = (const float*)d_in[12];
    const float* Wl  = (const float*)d_in[13];
    const float* Ul  = (const float*)d_in[14];
    const float* bl  = (const float*)d_in[15];
    const float* R1  = (const float*)d_in[16];
    const float* Rb1 = (const float*)d_in[17];
    const float* R2  = (const float*)d_in[18];
    const float* Rb2 = (const float*)d_in[19];
    const float* R3  = (const float*)d_in[20];
    const float* Rb3 = (const float*)d_in[21];

    char* w = (char*)d_ws;
    size_t off = 0;
    auto alloc = [&](size_t bytes) {
        char* p = w + off;
        off += (bytes + 255) & ~(size_t)255;
        return p;
    };
    float*          path_state = (float*)alloc((size_t)NP * DIM * 4);
    float*          link_state = (float*)alloc((size_t)NLINKS * DIM * 4);
    float*          m          = (float*)alloc((size_t)E_TOT * DIM * 4);
    unsigned short* ls_hi      = (unsigned short*)alloc((size_t)NLINKS * DIM * 2);
    unsigned short* ls_lo      = (unsigned short*)alloc((size_t)NLINKS * DIM * 2);
    unsigned short* wfr        = (unsigned short*)alloc(4 * 3072 * 2);
    unsigned short* lfr        = (unsigned short*)alloc(4 * 3072 * 2);
    unsigned short* rfr        = (unsigned short*)alloc((size_t)(8192 + 65536) * 2 * 2);
    int*            cnt        = (int*)alloc((size_t)NLINKS * 4);
    int*            row_start  = (int*)alloc((size_t)(NLINKS + 1) * 4);
    int*            cursor     = (int*)alloc((size_t)NLINKS * 4);
    int*            slot       = (int*)alloc((size_t)E_TOT * 4);

    hipMemsetAsync(cnt, 0, (size_t)NLINKS * 4, stream);
    // init + csr_count merged (one dispatch over E_TOT)
    init_kernel<<<(E_TOT + 255) / 256, 256, 0, stream>>>(links, cap, pol, wts, bw, tos,
                                                         pk, avg, link_state, path_state,
                                                         ls_hi, ls_lo, cnt);
    // scan + all weight-fragment prep merged (block 0 = scan)
    prep_kernel<<<1 + 12 + 12 + 288, 256, 0, stream>>>(cnt, row_start, cursor,
                                                       Wp, Up, wfr, Wl, Ul, lfr,
                                                       R1, R2, rfr);
    csr_scatter<<<(E_TOT + 255) / 256, 256, 0, stream>>>(links, cursor, slot);

    const int PGRID = (NP / 16 + 3) / 4;
    const int LGRID = (NLINKS / 16 + 3) / 4;
    for (int it = 0; it < TITERS - 1; ++it) {
        path_kernel<<<PGRID, 256, 0, stream>>>(links, wfr, bp, ls_hi, ls_lo,
                                               slot, path_state, m);
        aglk_kernel<<<LGRID, 256, 0, stream>>>(row_start, m, lfr, bl,
                                               link_state, ls_hi, ls_lo);
    }
    // final path iteration fused into readout
    readout_kernel<<<(NP / 16 + 1) / 2, 128, 0, stream>>>(links, wfr, bp, ls_hi, ls_lo,
                                                          path_state, rfr, Rb1, Rb2,
                                                          R3, Rb3, (float*)d_out);
}